// Round 11
// baseline (1288.149 us; speedup 1.0000x reference)
//
#include <hip/hip_runtime.h>
#include <hip/hip_bf16.h>

#define TT 4096L
#define HH 4096L
#define II 11008L
#define NSLOT 8

typedef short bf16x8 __attribute__((ext_vector_type(8)));
typedef float f32x4  __attribute__((ext_vector_type(4)));
typedef float f32x16 __attribute__((ext_vector_type(16)));

#define WAIT_VM6() asm volatile("s_waitcnt vmcnt(6)" ::: "memory")
#define WAIT_VM0() asm volatile("s_waitcnt vmcnt(0)" ::: "memory")
#define SBAR() __builtin_amdgcn_s_barrier()
#define SCHED0() __builtin_amdgcn_sched_barrier(0)

#define G1_NGEMM 1376   // 16 m-tiles x 86 n-tiles, 4m x 8n XCD bricks
#define G1_NAUX  2304   // 256 dwb-cvt blocks + 2048 psum blocks

typedef unsigned short u16;

__device__ __forceinline__ u16 f2bf(float v) {
  union { float f; unsigned int u; } c; c.f = v;
  unsigned int u = c.u;
  u += 0x7fffu + ((u >> 16) & 1u);
  return (u16)(u >> 16);
}

__device__ __forceinline__ void load_lds16(const void* g, void* lds) {
  __builtin_amdgcn_global_load_lds(
      (const __attribute__((address_space(1))) unsigned int*)g,
      (__attribute__((address_space(3))) unsigned int*)lds, 16, 0, 0);
}

__device__ __forceinline__ ushort4 cvt4(float4 v) {
  ushort4 o;
  o.x = f2bf(v.x); o.y = f2bf(v.y); o.z = f2bf(v.z); o.w = f2bf(v.w);
  return o;
}

// ---------- fused convert+prep: xb, gup pack, bucket, wab, wdb ----------
__global__ __launch_bounds__(256) void cvt_all_kernel(
    const float* __restrict__ x, u16* __restrict__ xb,
    const float* __restrict__ guw, u16* __restrict__ gup,
    const int* __restrict__ tix, int* __restrict__ cnt,
    int* __restrict__ off, int* __restrict__ list,
    const float* __restrict__ rg, const float* __restrict__ ru,
    const float* __restrict__ fg, const float* __restrict__ fu,
    u16* __restrict__ wab,
    const float* __restrict__ rd, const float* __restrict__ fd,
    u16* __restrict__ wdb) {
  int bid = blockIdx.x;
  int tid = threadIdx.x;
  if (bid < 2048) {
    const long NX = TT * HH / 4;
    const long NG = 2L * II * HH / 4;
    long i = (long)bid * 256 + tid;
    for (; i < NX + NG; i += 2048L * 256) {
      if (i < NX) {
        ((ushort4*)xb)[i] = cvt4(((const float4*)x)[i]);
      } else {
        long g = i - NX;
        long grow = g >> 10;
        long q = g & 1023;
        long c16 = grow >> 5;
        int r = (int)(grow & 31);
        long src = (r < 16) ? (c16 * 16 + r) : (II + c16 * 16 + (r - 16));
        ((ushort4*)gup)[g] = cvt4(((const float4*)guw)[src * 1024 + q]);
      }
    }
    return;
  }
  int pb = bid - 2048;    // 0: bucket, 1..256: wab, 257..384: wdb
  if (pb == 0) {
    __shared__ int lc[NSLOT], lo[NSLOT], pc[NSLOT];
    if (tid < NSLOT) { lc[tid] = 0; pc[tid] = 0; }
    __syncthreads();
    for (int t = tid; t < TT; t += 256) atomicAdd(&lc[tix[t]], 1);
    __syncthreads();
    if (tid == 0) {
      int s = 0;
      for (int i = 0; i < NSLOT; ++i) { lo[i] = s; s += lc[i]; }
    }
    __syncthreads();
    for (int t = tid; t < TT; t += 256) {
      int s = tix[t];
      int p = atomicAdd(&pc[s], 1);
      list[lo[s] + p] = t;
    }
    if (tid < NSLOT) { cnt[tid] = lc[tid]; off[tid] = lo[tid]; }
  } else if (pb <= 256) {
    const long Q = 8L * 256 * HH / 4;
    long i = (long)(pb - 1) * 256 + tid;
    for (; i < Q; i += 256L * 256) {
      long grow = i >> 10, q = i & 1023;
      int s = (int)(grow >> 8), r = (int)(grow & 255);
      const float* src;
      int rr = r & 63;
      if (r < 64) src = rg; else if (r < 128) src = ru;
      else if (r < 192) src = fg; else src = fu;
      ((ushort4*)wab)[i] = cvt4(((const float4*)src)[((long)s * 64 + rr) * 1024 + q]);
    }
  } else {
    const long Q = 8L * HH * 128 / 4;
    long i = (long)(pb - 257) * 256 + tid;
    for (; i < Q; i += 128L * 256) {
      long rowg = i >> 5;
      int q = (int)(i & 31);
      float4 v = (q < 16) ? ((const float4*)rd)[rowg * 16 + q]
                          : ((const float4*)fd)[rowg * 16 + (q - 16)];
      ((ushort4*)wdb)[i] = cvt4(v);
    }
  }
}

// =====================================================================
// Adapter phase 1 body (MFMA 16x16, split-K=4) — shared standalone + aux.
// =====================================================================
__device__ __forceinline__ void psum_body(
    char* lds, const u16* __restrict__ xb, const u16* __restrict__ wab,
    const int* __restrict__ cnt, const int* __restrict__ off,
    const int* __restrict__ list, float* __restrict__ psum,
    int s, int c, int kq, int tid) {
  int n = cnt[s];
  if (c * 64 >= n) return;
  int* tl = (int*)(lds + 81920);
  int base = off[s] + c * 64;
  int ntok = min(64, n - c * 64);
  if (tid < 64) tl[tid] = (tid < ntok) ? list[base + tid] : list[base];
  __syncthreads();
  const int w = tid >> 6, l = tid & 63, l16 = l & 15, lq = l >> 4;
  const int sslot = (tid & 7) ^ ((tid >> 3) & 7);
  const long kbase = (long)kq * 1024;
  const u16* xsrc = xb + (size_t)tl[tid >> 3] * HH + kbase + sslot * 8;
  const u16* wsrc = wab + ((size_t)s * 256 + (tid >> 3)) * HH + kbase + sslot * 8;
  const int wdst = w * 1024;

#define PS_STAGE(buf, t) do { \
    load_lds16(xsrc + (long)(t) * 64, lds + (buf) + wdst); \
    _Pragma("unroll") for (int r = 0; r < 4; ++r) \
      load_lds16(wsrc + (size_t)(r * 64) * HH + (long)(t) * 64, \
                 lds + (buf) + 8192 + r * 8192 + wdst); } while (0)

  const int sw = l16 & 7;
  f32x4 acc[4][2];
#pragma unroll
  for (int i = 0; i < 4; ++i)
#pragma unroll
    for (int j = 0; j < 2; ++j) acc[i][j] = (f32x4)0.f;

  PS_STAGE(0, 0);
  __syncthreads();
  for (int t = 0; t < 16; ++t) {
    const int cb = (t & 1) * 40960;
    if (t + 1 < 16) PS_STAGE(cb ^ 40960, t + 1);
    const char* Lb = lds + cb;
    bf16x8 av[4][2], bv[2][2];
#pragma unroll
    for (int i = 0; i < 4; ++i)
#pragma unroll
      for (int kh = 0; kh < 2; ++kh)
        av[i][kh] = *(const bf16x8*)(Lb + (i * 16 + l16) * 128 + (((kh * 4 + lq) ^ sw) * 16));
#pragma unroll
    for (int j = 0; j < 2; ++j)
#pragma unroll
      for (int kh = 0; kh < 2; ++kh)
        bv[j][kh] = *(const bf16x8*)(Lb + 8192 + (w * 32 + j * 16 + l16) * 128 + (((kh * 4 + lq) ^ sw) * 16));
#pragma unroll
    for (int i = 0; i < 4; ++i)
#pragma unroll
      for (int j = 0; j < 2; ++j) {
        acc[i][j] = __builtin_amdgcn_mfma_f32_16x16x32_bf16(av[i][0], bv[j][0], acc[i][j], 0, 0, 0);
        acc[i][j] = __builtin_amdgcn_mfma_f32_16x16x32_bf16(av[i][1], bv[j][1], acc[i][j], 0, 0, 0);
      }
    __syncthreads();
  }
  float* pb = psum + (size_t)kq * TT * 256;
#pragma unroll
  for (int i = 0; i < 4; ++i)
#pragma unroll
    for (int j = 0; j < 2; ++j)
#pragma unroll
      for (int r = 0; r < 4; ++r) {
        int tk = i * 16 + lq * 4 + r;
        pb[(size_t)tl[tk] * 256 + w * 32 + j * 16 + l16] = acc[i][j][r];
      }
#undef PS_STAGE
}

__global__ __launch_bounds__(512) void adapter_psum_kernel(
    const u16* __restrict__ xb, const u16* __restrict__ wab,
    const int* __restrict__ cnt, const int* __restrict__ off,
    const int* __restrict__ list, float* __restrict__ psum) {
  extern __shared__ char lds[];
  psum_body(lds, xb, wab, cnt, off, list, psum,
            blockIdx.x, blockIdx.y, blockIdx.z, threadIdx.x);
}

// ---------- reduce split-K + SwiGLU + scale -> irb bf16 [T][128] ----------
__global__ __launch_bounds__(256) void adapter_reduce_kernel(
    const float* __restrict__ psum, const float* __restrict__ scales,
    const int* __restrict__ tix, u16* __restrict__ irb) {
  int idx = blockIdx.x * 256 + threadIdx.x;
  int t = idx >> 7, n = idx & 127;
  int a = n >> 6, nn = n & 63;
  int cg = a ? 128 + nn : nn;
  size_t b = (size_t)t * 256;
  float g = 0.f, u = 0.f;
#pragma unroll
  for (int kq = 0; kq < 4; ++kq) {
    g += psum[(size_t)kq * TT * 256 + b + cg];
    u += psum[(size_t)kq * TT * 256 + b + cg + 64];
  }
  float sc = scales[tix[t] * 2 + a];
  float sv = g / (1.f + __expf(-g));
  irb[idx] = f2bf(sv * u * sc);
}

// =====================================================================
// Adapter phase 2 (MFMA 16x16): out[t][h] += irb[t][:] @ wdb[s][h][:]^T
// =====================================================================
__global__ __launch_bounds__(512) void adapter_down2_kernel(
    const u16* __restrict__ irb, const u16* __restrict__ wdb,
    const int* __restrict__ cnt, const int* __restrict__ off,
    const int* __restrict__ list, float* __restrict__ out) {
  extern __shared__ char lds[];
  __shared__ int tl[64];
  int s = blockIdx.x, c = blockIdx.y, hb = blockIdx.z;
  int n = cnt[s];
  if (c * 64 >= n) return;
  int base = off[s] + c * 64;
  int ntok = min(64, n - c * 64);
  int tid = threadIdx.x;
  if (tid < 64) tl[tid] = (tid < ntok) ? list[base + tid] : list[base];
  __syncthreads();
  const int w = tid >> 6, l = tid & 63, l16 = l & 15, lq = l >> 4;
  const int sslot = (tid & 15) ^ ((tid >> 4) & 15);
  const int wdst = w * 1024;
  const u16* isrc0 = irb + (size_t)tl[tid >> 4] * 128 + sslot * 8;
  const u16* isrc1 = irb + (size_t)tl[32 + (tid >> 4)] * 128 + sslot * 8;
  const u16* wsrc =
      wdb + ((size_t)s * HH + hb * 256 + (tid >> 4)) * 128 + sslot * 8;
  load_lds16(isrc0, lds + wdst);
  load_lds16(isrc1, lds + 8192 + wdst);
#pragma unroll
  for (int r = 0; r < 8; ++r)
    load_lds16(wsrc + (size_t)r * 4096, lds + 16384 + r * 8192 + wdst);
  __syncthreads();

  f32x4 acc[4][2];
#pragma unroll
  for (int i = 0; i < 4; ++i)
#pragma unroll
    for (int j = 0; j < 2; ++j) acc[i][j] = (f32x4)0.f;

#pragma unroll
  for (int kf = 0; kf < 4; ++kf) {
    bf16x8 av[4], bv[2];
#pragma unroll
    for (int i = 0; i < 4; ++i)
      av[i] = *(const bf16x8*)(lds + (i * 16 + l16) * 256 + (((kf * 4 + lq) ^ l16) * 16));
#pragma unroll
    for (int j = 0; j < 2; ++j)
      bv[j] = *(const bf16x8*)(lds + 16384 + (w * 32 + j * 16 + l16) * 256 + (((kf * 4 + lq) ^ l16) * 16));
#pragma unroll
    for (int i = 0; i < 4; ++i)
#pragma unroll
      for (int j = 0; j < 2; ++j)
        acc[i][j] = __builtin_amdgcn_mfma_f32_16x16x32_bf16(av[i], bv[j], acc[i][j], 0, 0, 0);
  }
#pragma unroll
  for (int i = 0; i < 4; ++i)
#pragma unroll
    for (int j = 0; j < 2; ++j)
#pragma unroll
      for (int r = 0; r < 4; ++r) {
        int tk = i * 16 + lq * 4 + r;
        if (tk < ntok) {
          size_t o = (size_t)tl[tk] * HH + hb * 256 + w * 32 + j * 16 + l16;
          out[o] += acc[i][j][r];
        }
      }
}

// =====================================================================
// GEMM2: C = inter @ down_w^T — 256x256, BK=64, 8-phase staggered frags,
// 4m x 8n XCD bricks, mfma_f32_32x32x16_bf16.
// A/B frag: row=l&31, k=(l>>5)*8+j.  C/D: col=l&31, row=(r&3)+8(r>>2)+4(l>>5).
// =====================================================================
__global__ __launch_bounds__(512, 2) void gemm2_8p_kernel(
    const u16* __restrict__ A,
    const u16* __restrict__ B,
    float* __restrict__ C) {
  extern __shared__ char lds[];
  const long K = II;
  const int NT = (int)(K >> 6);
  const int tid = threadIdx.x;
  const int w = tid >> 6, l = tid & 63;
  const int l31 = l & 31, lhi = l >> 5, l7 = l & 7;
  const int wm = w >> 2, wn = w & 3;
  const int lin = blockIdx.y * 16 + blockIdx.x;      // nwg=256
  const int xc = lin & 7, rr_ = lin >> 3;
  const long m0 = (long)((xc >> 1) * 4 + (rr_ & 3)) * 256;
  const long n0 = (long)((xc & 1) * 8 + (rr_ >> 2)) * 256;
  const int wb = w * 1024;

  const int srow = tid >> 3;
  const int sslot = (tid & 7) ^ (srow & 7);
  const u16* sA00 = A + (m0 +       srow) * K + sslot * 8;
  const u16* sA01 = A + (m0 +  64 + srow) * K + sslot * 8;
  const u16* sA10 = A + (m0 + 128 + srow) * K + sslot * 8;
  const u16* sA11 = A + (m0 + 192 + srow) * K + sslot * 8;
  const u16* sB00 = B + (n0 +       srow) * K + sslot * 8;
  const u16* sB01 = B + (n0 +  64 + srow) * K + sslot * 8;
  const u16* sB10 = B + (n0 + 128 + srow) * K + sslot * 8;
  const u16* sB11 = B + (n0 + 192 + srow) * K + sslot * 8;

#define G2_STAGE_A0(bb, kt) do { \
    load_lds16(sA00 + (long)(kt) * 64, lds + (bb) + wb); \
    load_lds16(sA01 + (long)(kt) * 64, lds + (bb) + 8192 + wb); } while (0)
#define G2_STAGE_A1(bb, kt) do { \
    load_lds16(sA10 + (long)(kt) * 64, lds + (bb) + 16384 + wb); \
    load_lds16(sA11 + (long)(kt) * 64, lds + (bb) + 24576 + wb); } while (0)
#define G2_STAGE_B0(bb, kt) do { \
    load_lds16(sB00 + (long)(kt) * 64, lds + (bb) + 32768 + wb); \
    load_lds16(sB01 + (long)(kt) * 64, lds + (bb) + 40960 + wb); } while (0)
#define G2_STAGE_B1(bb, kt) do { \
    load_lds16(sB10 + (long)(kt) * 64, lds + (bb) + 49152 + wb); \
    load_lds16(sB11 + (long)(kt) * 64, lds + (bb) + 57344 + wb); } while (0)

  // frag byte offsets (within A-half / B-half region)
  int aoffk[2][4], boffk[4];
#pragma unroll
  for (int bm = 0; bm < 2; ++bm)
#pragma unroll
    for (int ks = 0; ks < 4; ++ks)
      aoffk[bm][ks] = (wm * 64 + bm * 32 + l31) * 128 + (((ks * 2 + lhi) ^ l7) * 16);
#pragma unroll
  for (int ks = 0; ks < 4; ++ks)
    boffk[ks] = (wn * 32 + l31) * 128 + (((ks * 2 + lhi) ^ l7) * 16);

  f32x16 acc[4][2];
#pragma unroll
  for (int t = 0; t < 4; ++t)
#pragma unroll
    for (int bn = 0; bn < 2; ++bn) acc[t][bn] = (f32x16)0.f;

  G2_STAGE_A0(0, 0); G2_STAGE_A1(0, 0); G2_STAGE_B0(0, 0); G2_STAGE_B1(0, 0);
  G2_STAGE_A0(65536, 1); G2_STAGE_B1(65536, 1); G2_STAGE_A1(65536, 1);
  WAIT_VM6();
  SBAR();

  bf16x8 af[2][4], b0v[4], b1v[4];
#pragma unroll
  for (int bm = 0; bm < 2; ++bm)
#pragma unroll
    for (int ks = 0; ks < 4; ++ks)
      af[bm][ks] = *(const bf16x8*)(lds + aoffk[bm][ks]);
#pragma unroll
  for (int ks = 0; ks < 4; ++ks)
    b0v[ks] = *(const bf16x8*)(lds + 32768 + boffk[ks]);

#define G2_MFMA(qm, qn, bset) do { \
    __builtin_amdgcn_s_setprio(1); \
    _Pragma("unroll") for (int ks = 0; ks < 4; ++ks) \
      _Pragma("unroll") for (int bm = 0; bm < 2; ++bm) \
        acc[(qm) * 2 + bm][qn] = __builtin_amdgcn_mfma_f32_32x32x16_bf16( \
            af[bm][ks], bset[ks], acc[(qm) * 2 + bm][qn], 0, 0, 0); \
    __builtin_amdgcn_s_setprio(0); } while (0)

  for (int kt = 0; kt < NT; ++kt) {
    const int bb = (kt & 1) << 16;
    const int ob = bb ^ 65536;
    const char* Lb = lds + bb;
    // P0: pre-read B1 frags; stage B0(kt+1); MFMA Q00
#pragma unroll
    for (int ks = 0; ks < 4; ++ks)
      b1v[ks] = *(const bf16x8*)(Lb + 49152 + boffk[ks]);
    if (kt + 1 < NT) G2_STAGE_B0(ob, kt + 1);
    SBAR(); SCHED0();
    G2_MFMA(0, 0, b0v);
    SCHED0(); SBAR();
    // P1: stage A0(kt+2); MFMA Q01; post-read A1 frags
    if (kt + 2 < NT) G2_STAGE_A0(bb, kt + 2);
    SBAR(); SCHED0();
    G2_MFMA(0, 1, b1v);
    SCHED0();
#pragma unroll
    for (int bm = 0; bm < 2; ++bm)
#pragma unroll
      for (int ks = 0; ks < 4; ++ks)
        af[bm][ks] = *(const bf16x8*)(Lb + 16384 + aoffk[bm][ks]);
    SBAR();
    // P2: stage B1(kt+2); MFMA Q11
    if (kt + 2 < NT) G2_STAGE_B1(bb, kt + 2);
    SBAR(); SCHED0();
    G2_MFMA(1, 1, b1v);
    SCHED0(); SBAR();
    // P3: stage A1(kt+2); MFMA Q10; vmcnt; barrier; next-tile reads
    if (kt + 2 < NT) G2_STAGE_A1(bb, kt + 2);
    SBAR(); SCHED0();
    G2_MFMA(1, 0, b0v);
    SCHED0();
    if (kt + 2 < NT) { WAIT_VM6(); } else { WAIT_VM0(); }
    SBAR();
    if (kt + 1 < NT) {
      const char* Lo = lds + ob;
#pragma unroll
      for (int bm = 0; bm < 2; ++bm)
#pragma unroll
        for (int ks = 0; ks < 4; ++ks)
          af[bm][ks] = *(const bf16x8*)(Lo + aoffk[bm][ks]);
#pragma unroll
      for (int ks = 0; ks < 4; ++ks)
        b0v[ks] = *(const bf16x8*)(Lo + 32768 + boffk[ks]);
    }
  }

#pragma unroll
  for (int t = 0; t < 4; ++t) {
    long mb = m0 + (t >> 1) * 128 + wm * 64 + (t & 1) * 32;
#pragma unroll
    for (int bn = 0; bn < 2; ++bn) {
      long col = n0 + bn * 128 + wn * 32 + l31;
#pragma unroll
      for (int r = 0; r < 16; ++r) {
        long m = mb + (r & 3) + 8 * (r >> 2) + 4 * lhi;
        C[m * HH + col] = acc[t][bn][r];
      }
    }
  }
#undef G2_STAGE_A0
#undef G2_STAGE_A1
#undef G2_STAGE_B0
#undef G2_STAGE_B1
#undef G2_MFMA
}

// =====================================================================
// GEMM1 fused: swiglu(X @ gup^T), mfma 32x32x16, 4m x 8n bricks,
// aux tail = dwb convert (aid<256) + adapter psum (aid>=256).
// gate/up pairing: virtual col v=n0+bn*128+wn*32+(l&31); gate lanes (l&16)==0,
// up at partner lane l^16 (same row: l>>5 preserved).
// =====================================================================
__global__ __launch_bounds__(512, 2) void gemm1_fused_kernel(
    const u16* __restrict__ A,     // xb [TT][HH]
    const u16* __restrict__ B,     // gup [2I][HH] paired
    u16* __restrict__ inter,       // [TT][II]
    int naux,
    const float* __restrict__ dww, u16* __restrict__ dwb,
    const u16* __restrict__ wab, float* __restrict__ psum,
    const int* __restrict__ cnt, const int* __restrict__ off,
    const int* __restrict__ list) {
  extern __shared__ char lds[];
  const int lin = blockIdx.x;
  const int tid = threadIdx.x;

  if (lin >= G1_NGEMM) {
    int aid = lin - G1_NGEMM;
    if (aid >= naux) return;
    if (aid < 256) {
      const long Q = HH * II / 4;
      long i = (long)aid * 512 + tid;
      for (; i < Q; i += 256L * 512)
        ((ushort4*)dwb)[i] = cvt4(((const float4*)dww)[i]);
    } else {
      int p = aid - 256;                     // [0, 2048)
      psum_body(lds, A, wab, cnt, off, list, psum,
                p & 7, (p >> 3) & 63, p >> 9, tid);
    }
    return;
  }

  // ---------------- GEMM path (4m x 8n brick mapping) ----------------
  const int xc = lin & 7, s = lin >> 3;     // s in [0,172)
  const int wv = s >> 5, rr_ = s & 31;
  const long m0 = (long)((xc >> 1) * 4 + (rr_ & 3)) * 256;
  const long n0 = (long)((xc & 1) * 43 + wv * 8 + (rr_ >> 2)) * 256;  // virtual

  const long K = HH;
  const int NT = (int)(K >> 6);             // 64
  const int w = tid >> 6, l = tid & 63;
  const int l31 = l & 31, lhi = l >> 5, l7 = l & 7;
  const int wm = w >> 2, wn = w & 3;
  const int wb = w * 1024;

  const int srow = tid >> 3;
  const int sslot = (tid & 7) ^ (srow & 7);
  const u16* sA00 = A + (m0 +       srow) * K + sslot * 8;
  const u16* sA01 = A + (m0 +  64 + srow) * K + sslot * 8;
  const u16* sA10 = A + (m0 + 128 + srow) * K + sslot * 8;
  const u16* sA11 = A + (m0 + 192 + srow) * K + sslot * 8;
  const u16* sB00 = B + (n0 +       srow) * K + sslot * 8;
  const u16* sB01 = B + (n0 +  64 + srow) * K + sslot * 8;
  const u16* sB10 = B + (n0 + 128 + srow) * K + sslot * 8;
  const u16* sB11 = B + (n0 + 192 + srow) * K + sslot * 8;

#define G1_STAGE_A0(bb, kt) do { \
    load_lds16(sA00 + (long)(kt) * 64, lds + (bb) + wb); \
    load_lds16(sA01 + (long)(kt) * 64, lds + (bb) + 8192 + wb); } while (0)
#define G1_STAGE_A1(bb, kt) do { \
    load_lds16(sA10 + (long)(kt) * 64, lds + (bb) + 16384 + wb); \
    load_lds16(sA11 + (long)(kt) * 64, lds + (bb) + 24576 + wb); } while (0)
#define G1_STAGE_B0(bb, kt) do { \
    load_lds16(sB00 + (long)(kt) * 64, lds + (bb) + 32768 + wb); \
    load_lds16(sB01 + (long)(kt) * 64, lds + (bb) + 40960 + wb); } while (0)
#define G1_STAGE_B1(bb, kt) do { \
    load_lds16(sB10 + (long)(kt) * 64, lds + (bb) + 49152 + wb); \
    load_lds16(sB11 + (long)(kt) * 64, lds + (bb) + 57344 + wb); } while (0)

  int aoffk[2][4], boffk[4];
#pragma unroll
  for (int bm = 0; bm < 2; ++bm)
#pragma unroll
    for (int ks = 0; ks < 4; ++ks)
      aoffk[bm][ks] = (wm * 64 + bm * 32 + l31) * 128 + (((ks * 2 + lhi) ^ l7) * 16);
#pragma unroll
  for (int ks = 0; ks < 4; ++ks)
    boffk[ks] = (wn * 32 + l31) * 128 + (((ks * 2 + lhi) ^ l7) * 16);

  f32x16 acc[4][2];
#pragma unroll
  for (int t = 0; t < 4; ++t)
#pragma unroll
    for (int bn = 0; bn < 2; ++bn) acc[t][bn] = (f32x16)0.f;

  G1_STAGE_A0(0, 0); G1_STAGE_A1(0, 0); G1_STAGE_B0(0, 0); G1_STAGE_B1(0, 0);
  G1_STAGE_A0(65536, 1); G1_STAGE_B1(65536, 1); G1_STAGE_A1(65536, 1);
  WAIT_VM6();
  SBAR();

  bf16x8 af[2][4], b0v[4], b1v[4];
#pragma unroll
  for (int bm = 0; bm < 2; ++bm)
#pragma unroll
    for (int ks = 0; ks < 4; ++ks)
      af[bm][ks] = *(const bf16x8*)(lds + aoffk[bm][ks]);
#pragma unroll
  for (int ks = 0; ks < 4; ++ks)
    b0v[ks] = *(const bf16x8*)(lds + 32768 + boffk[ks]);

#define G1_MFMA(qm, qn, bset) do { \
    __builtin_amdgcn_s_setprio(1); \
    _Pragma("unroll") for (int ks = 0; ks < 4; ++ks) \
      _Pragma("unroll") for (int bm = 0; bm < 2; ++bm) \
        acc[(qm) * 2 + bm][qn] = __builtin_amdgcn_mfma_f32_32x32x16_bf16( \
            af[bm][ks], bset[ks], acc[(qm) * 2 + bm][qn], 0, 0, 0); \
    __builtin_amdgcn_s_setprio(0); } while (0)

  for (int kt = 0; kt < NT; ++kt) {
    const int bb = (kt & 1) << 16;
    const int ob = bb ^ 65536;
    const char* Lb = lds + bb;
#pragma unroll
    for (int ks = 0; ks < 4; ++ks)
      b1v[ks] = *(const bf16x8*)(Lb + 49152 + boffk[ks]);
    if (kt + 1 < NT) G1_STAGE_B0(ob, kt + 1);
    SBAR(); SCHED0();
    G1_MFMA(0, 0, b0v);
    SCHED0(); SBAR();
    if (kt + 2 < NT) G1_STAGE_A0(bb, kt + 2);
    SBAR(); SCHED0();
    G1_MFMA(0, 1, b1v);
    SCHED0();
#pragma unroll
    for (int bm = 0; bm < 2; ++bm)
#pragma unroll
      for (int ks = 0; ks < 4; ++ks)
        af[bm][ks] = *(const bf16x8*)(Lb + 16384 + aoffk[bm][ks]);
    SBAR();
    if (kt + 2 < NT) G1_STAGE_B1(bb, kt + 2);
    SBAR(); SCHED0();
    G1_MFMA(1, 1, b1v);
    SCHED0(); SBAR();
    if (kt + 2 < NT) G1_STAGE_A1(bb, kt + 2);
    SBAR(); SCHED0();
    G1_MFMA(1, 0, b0v);
    SCHED0();
    if (kt + 2 < NT) { WAIT_VM6(); } else { WAIT_VM0(); }
    SBAR();
    if (kt + 1 < NT) {
      const char* Lo = lds + ob;
#pragma unroll
      for (int bm = 0; bm < 2; ++bm)
#pragma unroll
        for (int ks = 0; ks < 4; ++ks)
          af[bm][ks] = *(const bf16x8*)(Lo + aoffk[bm][ks]);
#pragma unroll
      for (int ks = 0; ks < 4; ++ks)
        b0v[ks] = *(const bf16x8*)(Lo + 32768 + boffk[ks]);
    }
  }

  // epilogue: gate lanes (l&16)==0 pair with up at lane l^16 (same row).
#pragma unroll
  for (int t = 0; t < 4; ++t) {
    long mb = m0 + (t >> 1) * 128 + wm * 64 + (t & 1) * 32;
#pragma unroll
    for (int bn = 0; bn < 2; ++bn) {
      long ic = (n0 + bn * 128 + wn * 32) / 2 + (l & 15);
#pragma unroll
      for (int r = 0; r < 16; ++r) {
        float v = acc[t][bn][r];
        float o = __shfl_xor(v, 16, 64);
        if (!(l & 16)) {
          float g = v, u = o;
          float sv = g / (1.f + __expf(-g));
          long m = mb + (r & 3) + 8 * (r >> 2) + 4 * lhi;
          inter[m * II + ic] = f2bf(sv * u);
        }
      }
    }
  }
#undef G1_STAGE_A0
#undef G1_STAGE_A1
#undef G1_STAGE_B0
#undef G1_STAGE_B1
#undef G1_MFMA
}

// ---------- launcher ----------
extern "C" void kernel_launch(void* const* d_in, const int* in_sizes, int n_in,
                              void* d_out, int out_size, void* d_ws, size_t ws_size,
                              hipStream_t stream) {
  const float* x   = (const float*)d_in[0];
  const float* guw = (const float*)d_in[1];
  const float* dww = (const float*)d_in[2];
  const float* rg  = (const float*)d_in[3];
  const float* ru  = (const float*)d_in[4];
  const float* rd  = (const float*)d_in[5];
  const float* fg  = (const float*)d_in[6];
  const float* fu  = (const float*)d_in[7];
  const float* fd  = (const float*)d_in[8];
  const float* sc  = (const float*)d_in[9];
  const int*   tix = (const int*)d_in[10];
  float* out = (float*)d_out;
  char* ws = (char*)d_ws;

  size_t o = 0;
  u16* xb            = (u16*)(ws + o); o += (size_t)TT * HH * 2;
  u16* gup           = (u16*)(ws + o); o += (size_t)2 * II * HH * 2;
  u16* dwb           = (u16*)(ws + o); o += (size_t)HH * II * 2;
  char* inter_base   = ws + o;         o += (size_t)TT * II * 2;
  u16* inter         = (u16*)inter_base;
  u16* wdb           = (u16*)(ws + o); o += (size_t)8 * HH * 128 * 2;
  u16* irb           = (u16*)(ws + o); o += (size_t)TT * 128 * 2;
  int* cntp          = (int*)(ws + o); o += 256;
  int* offp          = (int*)(ws + o); o += 256;
  int* listp         = (int*)(ws + o); o += (size_t)TT * 4;
  size_t o_shared = o;
  u16* wabA          = (u16*)(ws + o_shared);
  float* psumA       = (float*)(ws + o_shared + 16777216);
  size_t needA = o_shared + 16777216 + (size_t)4 * TT * 256 * 4;
  u16* wabB          = (u16*)inter_base;
  float* psumB       = (float*)(inter_base + 16777216);
  bool pathA = ws_size >= needA;
  u16* wab  = pathA ? wabA  : wabB;
  float* psum = pathA ? psumA : psumB;

  hipFuncSetAttribute((const void*)gemm1_fused_kernel,
                      hipFuncAttributeMaxDynamicSharedMemorySize, 131072);
  hipFuncSetAttribute((const void*)gemm2_8p_kernel,
                      hipFuncAttributeMaxDynamicSharedMemorySize, 131072);
  hipFuncSetAttribute((const void*)adapter_psum_kernel,
                      hipFuncAttributeMaxDynamicSharedMemorySize, 82176);
  hipFuncSetAttribute((const void*)adapter_down2_kernel,
                      hipFuncAttributeMaxDynamicSharedMemorySize, 81920);

  cvt_all_kernel<<<2433, 256, 0, stream>>>(
      x, xb, guw, gup, tix, cntp, offp, listp,
      rg, ru, fg, fu, wab, rd, fd, wdb);

  if (pathA) {
    gemm1_fused_kernel<<<G1_NGEMM + G1_NAUX, 512, 131072, stream>>>(
        xb, gup, inter, G1_NAUX, dww, dwb, wab, psum, cntp, offp, listp);
    adapter_reduce_kernel<<<2048, 256, 0, stream>>>(psum, sc, tix, irb);
  } else {
    adapter_psum_kernel<<<dim3(NSLOT, 64, 4), 512, 82176, stream>>>(
        xb, wab, cntp, offp, listp, psum);
    gemm1_fused_kernel<<<G1_NGEMM + 256, 512, 131072, stream>>>(
        xb, gup, inter, 256, dww, dwb, wab, psum, cntp, offp, listp);
    adapter_reduce_kernel<<<2048, 256, 0, stream>>>(psum, sc, tix, irb);
  }

  gemm2_8p_kernel<<<dim3(16, 16), 512, 131072, stream>>>(inter, dwb, out);
  adapter_down2_kernel<<<dim3(NSLOT, 64, 16), 512, 81920, stream>>>(
      irb, wdb, cntp, offp, listp, out);
}

// Round 12
// 1253.346 us; speedup vs baseline: 1.0278x; 1.0278x over previous
//
#include <hip/hip_runtime.h>
#include <hip/hip_bf16.h>

#define TT 4096L
#define HH 4096L
#define II 11008L
#define NSLOT 8

typedef short bf16x8 __attribute__((ext_vector_type(8)));
typedef float f32x4  __attribute__((ext_vector_type(4)));
typedef float f32x16 __attribute__((ext_vector_type(16)));

#define WAIT_VM6() asm volatile("s_waitcnt vmcnt(6)" ::: "memory")
#define WAIT_VM0() asm volatile("s_waitcnt vmcnt(0)" ::: "memory")
#define SBAR() __builtin_amdgcn_s_barrier()
#define SCHED0() __builtin_amdgcn_sched_barrier(0)

#define G1_NGEMM 1376   // 16 m-tiles x 86 n-tiles, 4m x 8n XCD bricks
#define G1_NAUX  2304   // 256 dwb-cvt blocks + 2048 psum blocks

typedef unsigned short u16;

__device__ __forceinline__ u16 f2bf(float v) {
  union { float f; unsigned int u; } c; c.f = v;
  unsigned int u = c.u;
  u += 0x7fffu + ((u >> 16) & 1u);
  return (u16)(u >> 16);
}

__device__ __forceinline__ void load_lds16(const void* g, void* lds) {
  __builtin_amdgcn_global_load_lds(
      (const __attribute__((address_space(1))) unsigned int*)g,
      (__attribute__((address_space(3))) unsigned int*)lds, 16, 0, 0);
}

__device__ __forceinline__ ushort4 cvt4(float4 v) {
  ushort4 o;
  o.x = f2bf(v.x); o.y = f2bf(v.y); o.z = f2bf(v.z); o.w = f2bf(v.w);
  return o;
}

// ---------- fused convert+prep: xb, gup pack (tile-split), bucket, wab, wdb ----------
// gup virtual row v: tile g = v>>8, r = v&255;
//   r<128 -> gate row g*128+r ; r>=128 -> up row g*128+(r-128)   (II = 86*128)
__global__ __launch_bounds__(256) void cvt_all_kernel(
    const float* __restrict__ x, u16* __restrict__ xb,
    const float* __restrict__ guw, u16* __restrict__ gup,
    const int* __restrict__ tix, int* __restrict__ cnt,
    int* __restrict__ off, int* __restrict__ list,
    const float* __restrict__ rg, const float* __restrict__ ru,
    const float* __restrict__ fg, const float* __restrict__ fu,
    u16* __restrict__ wab,
    const float* __restrict__ rd, const float* __restrict__ fd,
    u16* __restrict__ wdb) {
  int bid = blockIdx.x;
  int tid = threadIdx.x;
  if (bid < 2048) {
    const long NX = TT * HH / 4;
    const long NG = 2L * II * HH / 4;
    long i = (long)bid * 256 + tid;
    for (; i < NX + NG; i += 2048L * 256) {
      if (i < NX) {
        ((ushort4*)xb)[i] = cvt4(((const float4*)x)[i]);
      } else {
        long g4 = i - NX;
        long grow = g4 >> 10;          // virtual row (1024 float4/row)
        long q = g4 & 1023;
        long g = grow >> 8;
        int r = (int)(grow & 255);
        long src = (r < 128) ? (g * 128 + r) : (II + g * 128 + (r - 128));
        ((ushort4*)gup)[g4] = cvt4(((const float4*)guw)[src * 1024 + q]);
      }
    }
    return;
  }
  int pb = bid - 2048;    // 0: bucket, 1..256: wab, 257..384: wdb
  if (pb == 0) {
    __shared__ int lc[NSLOT], lo[NSLOT], pc[NSLOT];
    if (tid < NSLOT) { lc[tid] = 0; pc[tid] = 0; }
    __syncthreads();
    for (int t = tid; t < TT; t += 256) atomicAdd(&lc[tix[t]], 1);
    __syncthreads();
    if (tid == 0) {
      int s = 0;
      for (int i = 0; i < NSLOT; ++i) { lo[i] = s; s += lc[i]; }
    }
    __syncthreads();
    for (int t = tid; t < TT; t += 256) {
      int s = tix[t];
      int p = atomicAdd(&pc[s], 1);
      list[lo[s] + p] = t;
    }
    if (tid < NSLOT) { cnt[tid] = lc[tid]; off[tid] = lo[tid]; }
  } else if (pb <= 256) {
    const long Q = 8L * 256 * HH / 4;
    long i = (long)(pb - 1) * 256 + tid;
    for (; i < Q; i += 256L * 256) {
      long grow = i >> 10, q = i & 1023;
      int s = (int)(grow >> 8), r = (int)(grow & 255);
      const float* src;
      int rr = r & 63;
      if (r < 64) src = rg; else if (r < 128) src = ru;
      else if (r < 192) src = fg; else src = fu;
      ((ushort4*)wab)[i] = cvt4(((const float4*)src)[((long)s * 64 + rr) * 1024 + q]);
    }
  } else {
    const long Q = 8L * HH * 128 / 4;
    long i = (long)(pb - 257) * 256 + tid;
    for (; i < Q; i += 128L * 256) {
      long rowg = i >> 5;
      int q = (int)(i & 31);
      float4 v = (q < 16) ? ((const float4*)rd)[rowg * 16 + q]
                          : ((const float4*)fd)[rowg * 16 + (q - 16)];
      ((ushort4*)wdb)[i] = cvt4(v);
    }
  }
}

// =====================================================================
// Adapter phase 1 body (MFMA 16x16, split-K=4) — shared standalone + aux.
// =====================================================================
__device__ __forceinline__ void psum_body(
    char* lds, const u16* __restrict__ xb, const u16* __restrict__ wab,
    const int* __restrict__ cnt, const int* __restrict__ off,
    const int* __restrict__ list, float* __restrict__ psum,
    int s, int c, int kq, int tid) {
  int n = cnt[s];
  if (c * 64 >= n) return;
  int* tl = (int*)(lds + 81920);
  int base = off[s] + c * 64;
  int ntok = min(64, n - c * 64);
  if (tid < 64) tl[tid] = (tid < ntok) ? list[base + tid] : list[base];
  __syncthreads();
  const int w = tid >> 6, l = tid & 63, l16 = l & 15, lq = l >> 4;
  const int sslot = (tid & 7) ^ ((tid >> 3) & 7);
  const long kbase = (long)kq * 1024;
  const u16* xsrc = xb + (size_t)tl[tid >> 3] * HH + kbase + sslot * 8;
  const u16* wsrc = wab + ((size_t)s * 256 + (tid >> 3)) * HH + kbase + sslot * 8;
  const int wdst = w * 1024;

#define PS_STAGE(buf, t) do { \
    load_lds16(xsrc + (long)(t) * 64, lds + (buf) + wdst); \
    _Pragma("unroll") for (int r = 0; r < 4; ++r) \
      load_lds16(wsrc + (size_t)(r * 64) * HH + (long)(t) * 64, \
                 lds + (buf) + 8192 + r * 8192 + wdst); } while (0)

  const int sw = l16 & 7;
  f32x4 acc[4][2];
#pragma unroll
  for (int i = 0; i < 4; ++i)
#pragma unroll
    for (int j = 0; j < 2; ++j) acc[i][j] = (f32x4)0.f;

  PS_STAGE(0, 0);
  __syncthreads();
  for (int t = 0; t < 16; ++t) {
    const int cb = (t & 1) * 40960;
    if (t + 1 < 16) PS_STAGE(cb ^ 40960, t + 1);
    const char* Lb = lds + cb;
    bf16x8 av[4][2], bv[2][2];
#pragma unroll
    for (int i = 0; i < 4; ++i)
#pragma unroll
      for (int kh = 0; kh < 2; ++kh)
        av[i][kh] = *(const bf16x8*)(Lb + (i * 16 + l16) * 128 + (((kh * 4 + lq) ^ sw) * 16));
#pragma unroll
    for (int j = 0; j < 2; ++j)
#pragma unroll
      for (int kh = 0; kh < 2; ++kh)
        bv[j][kh] = *(const bf16x8*)(Lb + 8192 + (w * 32 + j * 16 + l16) * 128 + (((kh * 4 + lq) ^ sw) * 16));
#pragma unroll
    for (int i = 0; i < 4; ++i)
#pragma unroll
      for (int j = 0; j < 2; ++j) {
        acc[i][j] = __builtin_amdgcn_mfma_f32_16x16x32_bf16(av[i][0], bv[j][0], acc[i][j], 0, 0, 0);
        acc[i][j] = __builtin_amdgcn_mfma_f32_16x16x32_bf16(av[i][1], bv[j][1], acc[i][j], 0, 0, 0);
      }
    __syncthreads();
  }
  float* pb = psum + (size_t)kq * TT * 256;
#pragma unroll
  for (int i = 0; i < 4; ++i)
#pragma unroll
    for (int j = 0; j < 2; ++j)
#pragma unroll
      for (int r = 0; r < 4; ++r) {
        int tk = i * 16 + lq * 4 + r;
        pb[(size_t)tl[tk] * 256 + w * 32 + j * 16 + l16] = acc[i][j][r];
      }
#undef PS_STAGE
}

__global__ __launch_bounds__(512) void adapter_psum_kernel(
    const u16* __restrict__ xb, const u16* __restrict__ wab,
    const int* __restrict__ cnt, const int* __restrict__ off,
    const int* __restrict__ list, float* __restrict__ psum) {
  extern __shared__ char lds[];
  psum_body(lds, xb, wab, cnt, off, list, psum,
            blockIdx.x, blockIdx.y, blockIdx.z, threadIdx.x);
}

// ---------- reduce split-K + SwiGLU + scale -> irb bf16 [T][128] ----------
__global__ __launch_bounds__(256) void adapter_reduce_kernel(
    const float* __restrict__ psum, const float* __restrict__ scales,
    const int* __restrict__ tix, u16* __restrict__ irb) {
  int idx = blockIdx.x * 256 + threadIdx.x;
  int t = idx >> 7, n = idx & 127;
  int a = n >> 6, nn = n & 63;
  int cg = a ? 128 + nn : nn;
  size_t b = (size_t)t * 256;
  float g = 0.f, u = 0.f;
#pragma unroll
  for (int kq = 0; kq < 4; ++kq) {
    g += psum[(size_t)kq * TT * 256 + b + cg];
    u += psum[(size_t)kq * TT * 256 + b + cg + 64];
  }
  float sc = scales[tix[t] * 2 + a];
  float sv = g / (1.f + __expf(-g));
  irb[idx] = f2bf(sv * u * sc);
}

// =====================================================================
// Adapter phase 2 (MFMA 16x16): out[t][h] += irb[t][:] @ wdb[s][h][:]^T
// =====================================================================
__global__ __launch_bounds__(512) void adapter_down2_kernel(
    const u16* __restrict__ irb, const u16* __restrict__ wdb,
    const int* __restrict__ cnt, const int* __restrict__ off,
    const int* __restrict__ list, float* __restrict__ out) {
  extern __shared__ char lds[];
  __shared__ int tl[64];
  int s = blockIdx.x, c = blockIdx.y, hb = blockIdx.z;
  int n = cnt[s];
  if (c * 64 >= n) return;
  int base = off[s] + c * 64;
  int ntok = min(64, n - c * 64);
  int tid = threadIdx.x;
  if (tid < 64) tl[tid] = (tid < ntok) ? list[base + tid] : list[base];
  __syncthreads();
  const int w = tid >> 6, l = tid & 63, l16 = l & 15, lq = l >> 4;
  const int sslot = (tid & 15) ^ ((tid >> 4) & 15);
  const int wdst = w * 1024;
  const u16* isrc0 = irb + (size_t)tl[tid >> 4] * 128 + sslot * 8;
  const u16* isrc1 = irb + (size_t)tl[32 + (tid >> 4)] * 128 + sslot * 8;
  const u16* wsrc =
      wdb + ((size_t)s * HH + hb * 256 + (tid >> 4)) * 128 + sslot * 8;
  load_lds16(isrc0, lds + wdst);
  load_lds16(isrc1, lds + 8192 + wdst);
#pragma unroll
  for (int r = 0; r < 8; ++r)
    load_lds16(wsrc + (size_t)r * 4096, lds + 16384 + r * 8192 + wdst);
  __syncthreads();

  f32x4 acc[4][2];
#pragma unroll
  for (int i = 0; i < 4; ++i)
#pragma unroll
    for (int j = 0; j < 2; ++j) acc[i][j] = (f32x4)0.f;

#pragma unroll
  for (int kf = 0; kf < 4; ++kf) {
    bf16x8 av[4], bv[2];
#pragma unroll
    for (int i = 0; i < 4; ++i)
      av[i] = *(const bf16x8*)(lds + (i * 16 + l16) * 256 + (((kf * 4 + lq) ^ l16) * 16));
#pragma unroll
    for (int j = 0; j < 2; ++j)
      bv[j] = *(const bf16x8*)(lds + 16384 + (w * 32 + j * 16 + l16) * 256 + (((kf * 4 + lq) ^ l16) * 16));
#pragma unroll
    for (int i = 0; i < 4; ++i)
#pragma unroll
      for (int j = 0; j < 2; ++j)
        acc[i][j] = __builtin_amdgcn_mfma_f32_16x16x32_bf16(av[i], bv[j], acc[i][j], 0, 0, 0);
  }
#pragma unroll
  for (int i = 0; i < 4; ++i)
#pragma unroll
    for (int j = 0; j < 2; ++j)
#pragma unroll
      for (int r = 0; r < 4; ++r) {
        int tk = i * 16 + lq * 4 + r;
        if (tk < ntok) {
          size_t o = (size_t)tl[tk] * HH + hb * 256 + w * 32 + j * 16 + l16;
          out[o] += acc[i][j][r];
        }
      }
}

// =====================================================================
// GEMM2: C = inter @ down_w^T — 256x256, BK=64, 8-phase staggered frags,
// 4m x 8n XCD bricks, mfma_f32_32x32x16_bf16 (layouts verified r11).
// =====================================================================
__global__ __launch_bounds__(512, 2) void gemm2_8p_kernel(
    const u16* __restrict__ A,
    const u16* __restrict__ B,
    float* __restrict__ C) {
  extern __shared__ char lds[];
  const long K = II;
  const int NT = (int)(K >> 6);
  const int tid = threadIdx.x;
  const int w = tid >> 6, l = tid & 63;
  const int l31 = l & 31, lhi = l >> 5, l7 = l & 7;
  const int wm = w >> 2, wn = w & 3;
  const int lin = blockIdx.y * 16 + blockIdx.x;      // nwg=256
  const int xc = lin & 7, rr_ = lin >> 3;
  const long m0 = (long)((xc >> 1) * 4 + (rr_ & 3)) * 256;
  const long n0 = (long)((xc & 1) * 8 + (rr_ >> 2)) * 256;
  const int wb = w * 1024;

  const int srow = tid >> 3;
  const int sslot = (tid & 7) ^ (srow & 7);
  const u16* sA00 = A + (m0 +       srow) * K + sslot * 8;
  const u16* sA01 = A + (m0 +  64 + srow) * K + sslot * 8;
  const u16* sA10 = A + (m0 + 128 + srow) * K + sslot * 8;
  const u16* sA11 = A + (m0 + 192 + srow) * K + sslot * 8;
  const u16* sB00 = B + (n0 +       srow) * K + sslot * 8;
  const u16* sB01 = B + (n0 +  64 + srow) * K + sslot * 8;
  const u16* sB10 = B + (n0 + 128 + srow) * K + sslot * 8;
  const u16* sB11 = B + (n0 + 192 + srow) * K + sslot * 8;

#define G2_STAGE_A0(bb, kt) do { \
    load_lds16(sA00 + (long)(kt) * 64, lds + (bb) + wb); \
    load_lds16(sA01 + (long)(kt) * 64, lds + (bb) + 8192 + wb); } while (0)
#define G2_STAGE_A1(bb, kt) do { \
    load_lds16(sA10 + (long)(kt) * 64, lds + (bb) + 16384 + wb); \
    load_lds16(sA11 + (long)(kt) * 64, lds + (bb) + 24576 + wb); } while (0)
#define G2_STAGE_B0(bb, kt) do { \
    load_lds16(sB00 + (long)(kt) * 64, lds + (bb) + 32768 + wb); \
    load_lds16(sB01 + (long)(kt) * 64, lds + (bb) + 40960 + wb); } while (0)
#define G2_STAGE_B1(bb, kt) do { \
    load_lds16(sB10 + (long)(kt) * 64, lds + (bb) + 49152 + wb); \
    load_lds16(sB11 + (long)(kt) * 64, lds + (bb) + 57344 + wb); } while (0)

  int aoffk[2][4], boffk[4];
#pragma unroll
  for (int bm = 0; bm < 2; ++bm)
#pragma unroll
    for (int ks = 0; ks < 4; ++ks)
      aoffk[bm][ks] = (wm * 64 + bm * 32 + l31) * 128 + (((ks * 2 + lhi) ^ l7) * 16);
#pragma unroll
  for (int ks = 0; ks < 4; ++ks)
    boffk[ks] = (wn * 32 + l31) * 128 + (((ks * 2 + lhi) ^ l7) * 16);

  f32x16 acc[4][2];
#pragma unroll
  for (int t = 0; t < 4; ++t)
#pragma unroll
    for (int bn = 0; bn < 2; ++bn) acc[t][bn] = (f32x16)0.f;

  G2_STAGE_A0(0, 0); G2_STAGE_A1(0, 0); G2_STAGE_B0(0, 0); G2_STAGE_B1(0, 0);
  G2_STAGE_A0(65536, 1); G2_STAGE_B1(65536, 1); G2_STAGE_A1(65536, 1);
  WAIT_VM6();
  SBAR();

  bf16x8 af[2][4], b0v[4], b1v[4];
#pragma unroll
  for (int bm = 0; bm < 2; ++bm)
#pragma unroll
    for (int ks = 0; ks < 4; ++ks)
      af[bm][ks] = *(const bf16x8*)(lds + aoffk[bm][ks]);
#pragma unroll
  for (int ks = 0; ks < 4; ++ks)
    b0v[ks] = *(const bf16x8*)(lds + 32768 + boffk[ks]);

#define G2_MFMA(qm, qn, bset) do { \
    __builtin_amdgcn_s_setprio(1); \
    _Pragma("unroll") for (int ks = 0; ks < 4; ++ks) \
      _Pragma("unroll") for (int bm = 0; bm < 2; ++bm) \
        acc[(qm) * 2 + bm][qn] = __builtin_amdgcn_mfma_f32_32x32x16_bf16( \
            af[bm][ks], bset[ks], acc[(qm) * 2 + bm][qn], 0, 0, 0); \
    __builtin_amdgcn_s_setprio(0); } while (0)

  for (int kt = 0; kt < NT; ++kt) {
    const int bb = (kt & 1) << 16;
    const int ob = bb ^ 65536;
    const char* Lb = lds + bb;
#pragma unroll
    for (int ks = 0; ks < 4; ++ks)
      b1v[ks] = *(const bf16x8*)(Lb + 49152 + boffk[ks]);
    if (kt + 1 < NT) G2_STAGE_B0(ob, kt + 1);
    SBAR(); SCHED0();
    G2_MFMA(0, 0, b0v);
    SCHED0(); SBAR();
    if (kt + 2 < NT) G2_STAGE_A0(bb, kt + 2);
    SBAR(); SCHED0();
    G2_MFMA(0, 1, b1v);
    SCHED0();
#pragma unroll
    for (int bm = 0; bm < 2; ++bm)
#pragma unroll
      for (int ks = 0; ks < 4; ++ks)
        af[bm][ks] = *(const bf16x8*)(Lb + 16384 + aoffk[bm][ks]);
    SBAR();
    if (kt + 2 < NT) G2_STAGE_B1(bb, kt + 2);
    SBAR(); SCHED0();
    G2_MFMA(1, 1, b1v);
    SCHED0(); SBAR();
    if (kt + 2 < NT) G2_STAGE_A1(bb, kt + 2);
    SBAR(); SCHED0();
    G2_MFMA(1, 0, b0v);
    SCHED0();
    if (kt + 2 < NT) { WAIT_VM6(); } else { WAIT_VM0(); }
    SBAR();
    if (kt + 1 < NT) {
      const char* Lo = lds + ob;
#pragma unroll
      for (int bm = 0; bm < 2; ++bm)
#pragma unroll
        for (int ks = 0; ks < 4; ++ks)
          af[bm][ks] = *(const bf16x8*)(Lo + aoffk[bm][ks]);
#pragma unroll
      for (int ks = 0; ks < 4; ++ks)
        b0v[ks] = *(const bf16x8*)(Lo + 32768 + boffk[ks]);
    }
  }

#pragma unroll
  for (int t = 0; t < 4; ++t) {
    long mb = m0 + (t >> 1) * 128 + wm * 64 + (t & 1) * 32;
#pragma unroll
    for (int bn = 0; bn < 2; ++bn) {
      long col = n0 + bn * 128 + wn * 32 + l31;
#pragma unroll
      for (int r = 0; r < 16; ++r) {
        long m = mb + (r & 3) + 8 * (r >> 2) + 4 * lhi;
        C[m * HH + col] = acc[t][bn][r];
      }
    }
  }
#undef G2_STAGE_A0
#undef G2_STAGE_A1
#undef G2_STAGE_B0
#undef G2_STAGE_B1
#undef G2_MFMA
}

// =====================================================================
// GEMM1 fused: swiglu(X @ gup^T), mfma 32x32x16, 4m x 8n bricks.
// gup tile-split pack: B-tile rows 0-127 = gate, 128-255 = up for the
// SAME 128 inter cols -> acc[t][0]=gate, acc[t][1]=up, SAME lane+reg.
// Epilogue: pure VALU, no shfl, all lanes store.
// =====================================================================
__global__ __launch_bounds__(512, 2) void gemm1_fused_kernel(
    const u16* __restrict__ A,     // xb [TT][HH]
    const u16* __restrict__ B,     // gup [2I][HH] tile-split packed
    u16* __restrict__ inter,       // [TT][II]
    int naux,
    const float* __restrict__ dww, u16* __restrict__ dwb,
    const u16* __restrict__ wab, float* __restrict__ psum,
    const int* __restrict__ cnt, const int* __restrict__ off,
    const int* __restrict__ list) {
  extern __shared__ char lds[];
  const int lin = blockIdx.x;
  const int tid = threadIdx.x;

  if (lin >= G1_NGEMM) {
    int aid = lin - G1_NGEMM;
    if (aid >= naux) return;
    if (aid < 256) {
      const long Q = HH * II / 4;
      long i = (long)aid * 512 + tid;
      for (; i < Q; i += 256L * 512)
        ((ushort4*)dwb)[i] = cvt4(((const float4*)dww)[i]);
    } else {
      int p = aid - 256;                     // [0, 2048)
      psum_body(lds, A, wab, cnt, off, list, psum,
                p & 7, (p >> 3) & 63, p >> 9, tid);
    }
    return;
  }

  // ---------------- GEMM path (4m x 8n brick mapping) ----------------
  const int xc = lin & 7, s = lin >> 3;     // s in [0,172)
  const int wv = s >> 5, rr_ = s & 31;
  const long m0 = (long)((xc >> 1) * 4 + (rr_ & 3)) * 256;
  const long n0 = (long)((xc & 1) * 43 + wv * 8 + (rr_ >> 2)) * 256;  // virtual

  const long K = HH;
  const int NT = (int)(K >> 6);             // 64
  const int w = tid >> 6, l = tid & 63;
  const int l31 = l & 31, lhi = l >> 5, l7 = l & 7;
  const int wm = w >> 2, wn = w & 3;
  const int wb = w * 1024;

  const int srow = tid >> 3;
  const int sslot = (tid & 7) ^ (srow & 7);
  const u16* sA00 = A + (m0 +       srow) * K + sslot * 8;
  const u16* sA01 = A + (m0 +  64 + srow) * K + sslot * 8;
  const u16* sA10 = A + (m0 + 128 + srow) * K + sslot * 8;
  const u16* sA11 = A + (m0 + 192 + srow) * K + sslot * 8;
  const u16* sB00 = B + (n0 +       srow) * K + sslot * 8;
  const u16* sB01 = B + (n0 +  64 + srow) * K + sslot * 8;
  const u16* sB10 = B + (n0 + 128 + srow) * K + sslot * 8;
  const u16* sB11 = B + (n0 + 192 + srow) * K + sslot * 8;

#define G1_STAGE_A0(bb, kt) do { \
    load_lds16(sA00 + (long)(kt) * 64, lds + (bb) + wb); \
    load_lds16(sA01 + (long)(kt) * 64, lds + (bb) + 8192 + wb); } while (0)
#define G1_STAGE_A1(bb, kt) do { \
    load_lds16(sA10 + (long)(kt) * 64, lds + (bb) + 16384 + wb); \
    load_lds16(sA11 + (long)(kt) * 64, lds + (bb) + 24576 + wb); } while (0)
#define G1_STAGE_B0(bb, kt) do { \
    load_lds16(sB00 + (long)(kt) * 64, lds + (bb) + 32768 + wb); \
    load_lds16(sB01 + (long)(kt) * 64, lds + (bb) + 40960 + wb); } while (0)
#define G1_STAGE_B1(bb, kt) do { \
    load_lds16(sB10 + (long)(kt) * 64, lds + (bb) + 49152 + wb); \
    load_lds16(sB11 + (long)(kt) * 64, lds + (bb) + 57344 + wb); } while (0)

  int aoffk[2][4], boffk[4];
#pragma unroll
  for (int bm = 0; bm < 2; ++bm)
#pragma unroll
    for (int ks = 0; ks < 4; ++ks)
      aoffk[bm][ks] = (wm * 64 + bm * 32 + l31) * 128 + (((ks * 2 + lhi) ^ l7) * 16);
#pragma unroll
  for (int ks = 0; ks < 4; ++ks)
    boffk[ks] = (wn * 32 + l31) * 128 + (((ks * 2 + lhi) ^ l7) * 16);

  f32x16 acc[4][2];
#pragma unroll
  for (int t = 0; t < 4; ++t)
#pragma unroll
    for (int bn = 0; bn < 2; ++bn) acc[t][bn] = (f32x16)0.f;

  G1_STAGE_A0(0, 0); G1_STAGE_A1(0, 0); G1_STAGE_B0(0, 0); G1_STAGE_B1(0, 0);
  G1_STAGE_A0(65536, 1); G1_STAGE_B1(65536, 1); G1_STAGE_A1(65536, 1);
  WAIT_VM6();
  SBAR();

  bf16x8 af[2][4], b0v[4], b1v[4];
#pragma unroll
  for (int bm = 0; bm < 2; ++bm)
#pragma unroll
    for (int ks = 0; ks < 4; ++ks)
      af[bm][ks] = *(const bf16x8*)(lds + aoffk[bm][ks]);
#pragma unroll
  for (int ks = 0; ks < 4; ++ks)
    b0v[ks] = *(const bf16x8*)(lds + 32768 + boffk[ks]);

#define G1_MFMA(qm, qn, bset) do { \
    __builtin_amdgcn_s_setprio(1); \
    _Pragma("unroll") for (int ks = 0; ks < 4; ++ks) \
      _Pragma("unroll") for (int bm = 0; bm < 2; ++bm) \
        acc[(qm) * 2 + bm][qn] = __builtin_amdgcn_mfma_f32_32x32x16_bf16( \
            af[bm][ks], bset[ks], acc[(qm) * 2 + bm][qn], 0, 0, 0); \
    __builtin_amdgcn_s_setprio(0); } while (0)

  for (int kt = 0; kt < NT; ++kt) {
    const int bb = (kt & 1) << 16;
    const int ob = bb ^ 65536;
    const char* Lb = lds + bb;
#pragma unroll
    for (int ks = 0; ks < 4; ++ks)
      b1v[ks] = *(const bf16x8*)(Lb + 49152 + boffk[ks]);
    if (kt + 1 < NT) G1_STAGE_B0(ob, kt + 1);
    SBAR(); SCHED0();
    G1_MFMA(0, 0, b0v);
    SCHED0(); SBAR();
    if (kt + 2 < NT) G1_STAGE_A0(bb, kt + 2);
    SBAR(); SCHED0();
    G1_MFMA(0, 1, b1v);
    SCHED0();
#pragma unroll
    for (int bm = 0; bm < 2; ++bm)
#pragma unroll
      for (int ks = 0; ks < 4; ++ks)
        af[bm][ks] = *(const bf16x8*)(Lb + 16384 + aoffk[bm][ks]);
    SBAR();
    if (kt + 2 < NT) G1_STAGE_B1(bb, kt + 2);
    SBAR(); SCHED0();
    G1_MFMA(1, 1, b1v);
    SCHED0(); SBAR();
    if (kt + 2 < NT) G1_STAGE_A1(bb, kt + 2);
    SBAR(); SCHED0();
    G1_MFMA(1, 0, b0v);
    SCHED0();
    if (kt + 2 < NT) { WAIT_VM6(); } else { WAIT_VM0(); }
    SBAR();
    if (kt + 1 < NT) {
      const char* Lo = lds + ob;
#pragma unroll
      for (int bm = 0; bm < 2; ++bm)
#pragma unroll
        for (int ks = 0; ks < 4; ++ks)
          af[bm][ks] = *(const bf16x8*)(Lo + aoffk[bm][ks]);
#pragma unroll
      for (int ks = 0; ks < 4; ++ks)
        b0v[ks] = *(const bf16x8*)(Lo + 32768 + boffk[ks]);
    }
  }

  // epilogue: acc[t][0]=gate, acc[t][1]=up for inter col ic (same lane/reg).
  {
    const long ic0 = (n0 >> 1);              // tile g * 128
    const long ic = ic0 + wn * 32 + l31;
#pragma unroll
    for (int t = 0; t < 4; ++t) {
      long mb = m0 + (t >> 1) * 128 + wm * 64 + (t & 1) * 32;
#pragma unroll
      for (int r = 0; r < 16; ++r) {
        float g = acc[t][0][r], u = acc[t][1][r];
        float sv = g / (1.f + __expf(-g));
        long m = mb + (r & 3) + 8 * (r >> 2) + 4 * lhi;
        inter[m * II + ic] = f2bf(sv * u);
      }
    }
  }
#undef G1_STAGE_A0
#undef G1_STAGE_A1
#undef G1_STAGE_B0
#undef G1_STAGE_B1
#undef G1_MFMA
}

// ---------- launcher ----------
extern "C" void kernel_launch(void* const* d_in, const int* in_sizes, int n_in,
                              void* d_out, int out_size, void* d_ws, size_t ws_size,
                              hipStream_t stream) {
  const float* x   = (const float*)d_in[0];
  const float* guw = (const float*)d_in[1];
  const float* dww = (const float*)d_in[2];
  const float* rg  = (const float*)d_in[3];
  const float* ru  = (const float*)d_in[4];
  const float* rd  = (const float*)d_in[5];
  const float* fg  = (const float*)d_in[6];
  const float* fu  = (const float*)d_in[7];
  const float* fd  = (const float*)d_in[8];
  const float* sc  = (const float*)d_in[9];
  const int*   tix = (const int*)d_in[10];
  float* out = (float*)d_out;
  char* ws = (char*)d_ws;

  size_t o = 0;
  u16* xb            = (u16*)(ws + o); o += (size_t)TT * HH * 2;
  u16* gup           = (u16*)(ws + o); o += (size_t)2 * II * HH * 2;
  u16* dwb           = (u16*)(ws + o); o += (size_t)HH * II * 2;
  char* inter_base   = ws + o;         o += (size_t)TT * II * 2;
  u16* inter         = (u16*)inter_base;
  u16* wdb           = (u16*)(ws + o); o += (size_t)8 * HH * 128 * 2;
  u16* irb           = (u16*)(ws + o); o += (size_t)TT * 128 * 2;
  int* cntp          = (int*)(ws + o); o += 256;
  int* offp          = (int*)(ws + o); o += 256;
  int* listp         = (int*)(ws + o); o += (size_t)TT * 4;
  size_t o_shared = o;
  u16* wabA          = (u16*)(ws + o_shared);
  float* psumA       = (float*)(ws + o_shared + 16777216);
  size_t needA = o_shared + 16777216 + (size_t)4 * TT * 256 * 4;
  u16* wabB          = (u16*)inter_base;
  float* psumB       = (float*)(inter_base + 16777216);
  bool pathA = ws_size >= needA;
  u16* wab  = pathA ? wabA  : wabB;
  float* psum = pathA ? psumA : psumB;

  hipFuncSetAttribute((const void*)gemm1_fused_kernel,
                      hipFuncAttributeMaxDynamicSharedMemorySize, 131072);
  hipFuncSetAttribute((const void*)gemm2_8p_kernel,
                      hipFuncAttributeMaxDynamicSharedMemorySize, 131072);
  hipFuncSetAttribute((const void*)adapter_psum_kernel,
                      hipFuncAttributeMaxDynamicSharedMemorySize, 82176);
  hipFuncSetAttribute((const void*)adapter_down2_kernel,
                      hipFuncAttributeMaxDynamicSharedMemorySize, 81920);

  cvt_all_kernel<<<2433, 256, 0, stream>>>(
      x, xb, guw, gup, tix, cntp, offp, listp,
      rg, ru, fg, fu, wab, rd, fd, wdb);

  if (pathA) {
    gemm1_fused_kernel<<<G1_NGEMM + G1_NAUX, 512, 131072, stream>>>(
        xb, gup, inter, G1_NAUX, dww, dwb, wab, psum, cntp, offp, listp);
    adapter_reduce_kernel<<<2048, 256, 0, stream>>>(psum, sc, tix, irb);
  } else {
    adapter_psum_kernel<<<dim3(NSLOT, 64, 4), 512, 82176, stream>>>(
        xb, wab, cntp, offp, listp, psum);
    gemm1_fused_kernel<<<G1_NGEMM + 256, 512, 131072, stream>>>(
        xb, gup, inter, 256, dww, dwb, wab, psum, cntp, offp, listp);
    adapter_reduce_kernel<<<2048, 256, 0, stream>>>(psum, sc, tix, irb);
  }

  gemm2_8p_kernel<<<dim3(16, 16), 512, 131072, stream>>>(inter, dwb, out);
  adapter_down2_kernel<<<dim3(NSLOT, 64, 16), 512, 81920, stream>>>(
      irb, wdb, cntp, offp, listp, out);
}

// Round 13
// 1214.029 us; speedup vs baseline: 1.0611x; 1.0324x over previous
//
#include <hip/hip_runtime.h>
#include <hip/hip_bf16.h>

#define TT 4096L
#define HH 4096L
#define II 11008L
#define NSLOT 8

typedef short bf16x8 __attribute__((ext_vector_type(8)));
typedef float f32x4  __attribute__((ext_vector_type(4)));
typedef float f32x16 __attribute__((ext_vector_type(16)));

#define WAIT_VM6() asm volatile("s_waitcnt vmcnt(6)" ::: "memory")
#define WAIT_VM0() asm volatile("s_waitcnt vmcnt(0)" ::: "memory")
#define SBAR() __builtin_amdgcn_s_barrier()
#define SCHED0() __builtin_amdgcn_sched_barrier(0)

#define G1_NGEMM 1376   // 16 m-tiles x 86 n-tiles, 4m x 8n XCD bricks
#define G1_NAUX  2304   // 256 dwb-cvt blocks + 2048 psum blocks

typedef unsigned short u16;

__device__ __forceinline__ u16 f2bf(float v) {
  union { float f; unsigned int u; } c; c.f = v;
  unsigned int u = c.u;
  u += 0x7fffu + ((u >> 16) & 1u);
  return (u16)(u >> 16);
}

__device__ __forceinline__ void load_lds16(const void* g, void* lds) {
  __builtin_amdgcn_global_load_lds(
      (const __attribute__((address_space(1))) unsigned int*)g,
      (__attribute__((address_space(3))) unsigned int*)lds, 16, 0, 0);
}

__device__ __forceinline__ ushort4 cvt4(float4 v) {
  ushort4 o;
  o.x = f2bf(v.x); o.y = f2bf(v.y); o.z = f2bf(v.z); o.w = f2bf(v.w);
  return o;
}

// ---------- fused convert+prep: xb, gup pack (tile-split), bucket, wab, wdb ----------
// gup virtual row v: tile g = v>>8, r = v&255;
//   r<128 -> gate row g*128+r ; r>=128 -> up row g*128+(r-128)   (II = 86*128)
__global__ __launch_bounds__(256) void cvt_all_kernel(
    const float* __restrict__ x, u16* __restrict__ xb,
    const float* __restrict__ guw, u16* __restrict__ gup,
    const int* __restrict__ tix, int* __restrict__ cnt,
    int* __restrict__ off, int* __restrict__ list,
    const float* __restrict__ rg, const float* __restrict__ ru,
    const float* __restrict__ fg, const float* __restrict__ fu,
    u16* __restrict__ wab,
    const float* __restrict__ rd, const float* __restrict__ fd,
    u16* __restrict__ wdb) {
  int bid = blockIdx.x;
  int tid = threadIdx.x;
  if (bid < 2048) {
    const long NX = TT * HH / 4;
    const long NG = 2L * II * HH / 4;
    long i = (long)bid * 256 + tid;
    for (; i < NX + NG; i += 2048L * 256) {
      if (i < NX) {
        ((ushort4*)xb)[i] = cvt4(((const float4*)x)[i]);
      } else {
        long g4 = i - NX;
        long grow = g4 >> 10;          // virtual row (1024 float4/row)
        long q = g4 & 1023;
        long g = grow >> 8;
        int r = (int)(grow & 255);
        long src = (r < 128) ? (g * 128 + r) : (II + g * 128 + (r - 128));
        ((ushort4*)gup)[g4] = cvt4(((const float4*)guw)[src * 1024 + q]);
      }
    }
    return;
  }
  int pb = bid - 2048;    // 0: bucket, 1..256: wab, 257..384: wdb
  if (pb == 0) {
    __shared__ int lc[NSLOT], lo[NSLOT], pc[NSLOT];
    if (tid < NSLOT) { lc[tid] = 0; pc[tid] = 0; }
    __syncthreads();
    for (int t = tid; t < TT; t += 256) atomicAdd(&lc[tix[t]], 1);
    __syncthreads();
    if (tid == 0) {
      int s = 0;
      for (int i = 0; i < NSLOT; ++i) { lo[i] = s; s += lc[i]; }
    }
    __syncthreads();
    for (int t = tid; t < TT; t += 256) {
      int s = tix[t];
      int p = atomicAdd(&pc[s], 1);
      list[lo[s] + p] = t;
    }
    if (tid < NSLOT) { cnt[tid] = lc[tid]; off[tid] = lo[tid]; }
  } else if (pb <= 256) {
    const long Q = 8L * 256 * HH / 4;
    long i = (long)(pb - 1) * 256 + tid;
    for (; i < Q; i += 256L * 256) {
      long grow = i >> 10, q = i & 1023;
      int s = (int)(grow >> 8), r = (int)(grow & 255);
      const float* src;
      int rr = r & 63;
      if (r < 64) src = rg; else if (r < 128) src = ru;
      else if (r < 192) src = fg; else src = fu;
      ((ushort4*)wab)[i] = cvt4(((const float4*)src)[((long)s * 64 + rr) * 1024 + q]);
    }
  } else {
    const long Q = 8L * HH * 128 / 4;
    long i = (long)(pb - 257) * 256 + tid;
    for (; i < Q; i += 128L * 256) {
      long rowg = i >> 5;
      int q = (int)(i & 31);
      float4 v = (q < 16) ? ((const float4*)rd)[rowg * 16 + q]
                          : ((const float4*)fd)[rowg * 16 + (q - 16)];
      ((ushort4*)wdb)[i] = cvt4(v);
    }
  }
}

// =====================================================================
// Adapter phase 1 body (MFMA 16x16, split-K=4) — unchanged, 0-conflict.
// =====================================================================
__device__ __forceinline__ void psum_body(
    char* lds, const u16* __restrict__ xb, const u16* __restrict__ wab,
    const int* __restrict__ cnt, const int* __restrict__ off,
    const int* __restrict__ list, float* __restrict__ psum,
    int s, int c, int kq, int tid) {
  int n = cnt[s];
  if (c * 64 >= n) return;
  int* tl = (int*)(lds + 81920);
  int base = off[s] + c * 64;
  int ntok = min(64, n - c * 64);
  if (tid < 64) tl[tid] = (tid < ntok) ? list[base + tid] : list[base];
  __syncthreads();
  const int w = tid >> 6, l = tid & 63, l16 = l & 15, lq = l >> 4;
  const int sslot = (tid & 7) ^ ((tid >> 3) & 7);
  const long kbase = (long)kq * 1024;
  const u16* xsrc = xb + (size_t)tl[tid >> 3] * HH + kbase + sslot * 8;
  const u16* wsrc = wab + ((size_t)s * 256 + (tid >> 3)) * HH + kbase + sslot * 8;
  const int wdst = w * 1024;

#define PS_STAGE(buf, t) do { \
    load_lds16(xsrc + (long)(t) * 64, lds + (buf) + wdst); \
    _Pragma("unroll") for (int r = 0; r < 4; ++r) \
      load_lds16(wsrc + (size_t)(r * 64) * HH + (long)(t) * 64, \
                 lds + (buf) + 8192 + r * 8192 + wdst); } while (0)

  const int sw = l16 & 7;
  f32x4 acc[4][2];
#pragma unroll
  for (int i = 0; i < 4; ++i)
#pragma unroll
    for (int j = 0; j < 2; ++j) acc[i][j] = (f32x4)0.f;

  PS_STAGE(0, 0);
  __syncthreads();
  for (int t = 0; t < 16; ++t) {
    const int cb = (t & 1) * 40960;
    if (t + 1 < 16) PS_STAGE(cb ^ 40960, t + 1);
    const char* Lb = lds + cb;
    bf16x8 av[4][2], bv[2][2];
#pragma unroll
    for (int i = 0; i < 4; ++i)
#pragma unroll
      for (int kh = 0; kh < 2; ++kh)
        av[i][kh] = *(const bf16x8*)(Lb + (i * 16 + l16) * 128 + (((kh * 4 + lq) ^ sw) * 16));
#pragma unroll
    for (int j = 0; j < 2; ++j)
#pragma unroll
      for (int kh = 0; kh < 2; ++kh)
        bv[j][kh] = *(const bf16x8*)(Lb + 8192 + (w * 32 + j * 16 + l16) * 128 + (((kh * 4 + lq) ^ sw) * 16));
#pragma unroll
    for (int i = 0; i < 4; ++i)
#pragma unroll
      for (int j = 0; j < 2; ++j) {
        acc[i][j] = __builtin_amdgcn_mfma_f32_16x16x32_bf16(av[i][0], bv[j][0], acc[i][j], 0, 0, 0);
        acc[i][j] = __builtin_amdgcn_mfma_f32_16x16x32_bf16(av[i][1], bv[j][1], acc[i][j], 0, 0, 0);
      }
    __syncthreads();
  }
  float* pb = psum + (size_t)kq * TT * 256;
#pragma unroll
  for (int i = 0; i < 4; ++i)
#pragma unroll
    for (int j = 0; j < 2; ++j)
#pragma unroll
      for (int r = 0; r < 4; ++r) {
        int tk = i * 16 + lq * 4 + r;
        pb[(size_t)tl[tk] * 256 + w * 32 + j * 16 + l16] = acc[i][j][r];
      }
#undef PS_STAGE
}

__global__ __launch_bounds__(512) void adapter_psum_kernel(
    const u16* __restrict__ xb, const u16* __restrict__ wab,
    const int* __restrict__ cnt, const int* __restrict__ off,
    const int* __restrict__ list, float* __restrict__ psum) {
  extern __shared__ char lds[];
  psum_body(lds, xb, wab, cnt, off, list, psum,
            blockIdx.x, blockIdx.y, blockIdx.z, threadIdx.x);
}

// ---------- reduce split-K + SwiGLU + scale -> irb bf16 [T][128] ----------
__global__ __launch_bounds__(256) void adapter_reduce_kernel(
    const float* __restrict__ psum, const float* __restrict__ scales,
    const int* __restrict__ tix, u16* __restrict__ irb) {
  int idx = blockIdx.x * 256 + threadIdx.x;
  int t = idx >> 7, n = idx & 127;
  int a = n >> 6, nn = n & 63;
  int cg = a ? 128 + nn : nn;
  size_t b = (size_t)t * 256;
  float g = 0.f, u = 0.f;
#pragma unroll
  for (int kq = 0; kq < 4; ++kq) {
    g += psum[(size_t)kq * TT * 256 + b + cg];
    u += psum[(size_t)kq * TT * 256 + b + cg + 64];
  }
  float sc = scales[tix[t] * 2 + a];
  float sv = g / (1.f + __expf(-g));
  irb[idx] = f2bf(sv * u * sc);
}

// =====================================================================
// Adapter phase 2 (MFMA 16x16): out[t][h] += irb[t][:] @ wdb[s][h][:]^T
// =====================================================================
__global__ __launch_bounds__(512) void adapter_down2_kernel(
    const u16* __restrict__ irb, const u16* __restrict__ wdb,
    const int* __restrict__ cnt, const int* __restrict__ off,
    const int* __restrict__ list, float* __restrict__ out) {
  extern __shared__ char lds[];
  __shared__ int tl[64];
  int s = blockIdx.x, c = blockIdx.y, hb = blockIdx.z;
  int n = cnt[s];
  if (c * 64 >= n) return;
  int base = off[s] + c * 64;
  int ntok = min(64, n - c * 64);
  int tid = threadIdx.x;
  if (tid < 64) tl[tid] = (tid < ntok) ? list[base + tid] : list[base];
  __syncthreads();
  const int w = tid >> 6, l = tid & 63, l16 = l & 15, lq = l >> 4;
  const int sslot = (tid & 15) ^ ((tid >> 4) & 15);
  const int wdst = w * 1024;
  const u16* isrc0 = irb + (size_t)tl[tid >> 4] * 128 + sslot * 8;
  const u16* isrc1 = irb + (size_t)tl[32 + (tid >> 4)] * 128 + sslot * 8;
  const u16* wsrc =
      wdb + ((size_t)s * HH + hb * 256 + (tid >> 4)) * 128 + sslot * 8;
  load_lds16(isrc0, lds + wdst);
  load_lds16(isrc1, lds + 8192 + wdst);
#pragma unroll
  for (int r = 0; r < 8; ++r)
    load_lds16(wsrc + (size_t)r * 4096, lds + 16384 + r * 8192 + wdst);
  __syncthreads();

  f32x4 acc[4][2];
#pragma unroll
  for (int i = 0; i < 4; ++i)
#pragma unroll
    for (int j = 0; j < 2; ++j) acc[i][j] = (f32x4)0.f;

#pragma unroll
  for (int kf = 0; kf < 4; ++kf) {
    bf16x8 av[4], bv[2];
#pragma unroll
    for (int i = 0; i < 4; ++i)
      av[i] = *(const bf16x8*)(lds + (i * 16 + l16) * 256 + (((kf * 4 + lq) ^ l16) * 16));
#pragma unroll
    for (int j = 0; j < 2; ++j)
      bv[j] = *(const bf16x8*)(lds + 16384 + (w * 32 + j * 16 + l16) * 256 + (((kf * 4 + lq) ^ l16) * 16));
#pragma unroll
    for (int i = 0; i < 4; ++i)
#pragma unroll
      for (int j = 0; j < 2; ++j)
        acc[i][j] = __builtin_amdgcn_mfma_f32_16x16x32_bf16(av[i], bv[j], acc[i][j], 0, 0, 0);
  }
#pragma unroll
  for (int i = 0; i < 4; ++i)
#pragma unroll
    for (int j = 0; j < 2; ++j)
#pragma unroll
      for (int r = 0; r < 4; ++r) {
        int tk = i * 16 + lq * 4 + r;
        if (tk < ntok) {
          size_t o = (size_t)tl[tk] * HH + hb * 256 + w * 32 + j * 16 + l16;
          out[o] += acc[i][j][r];
        }
      }
}

// =====================================================================
// GEMM2: 256x256, BK=64, 8-phase staggered, 4m x 8n bricks, 32x32x16.
// NEW LDS layout per 32-row group (4KB): [16 lds-rows x 256B], element
// (row,kslot) at grp*4096 + (row&15)*256 + ((kslot*2+((row>>4)&1)) ^ (row&15))*16.
// Every 16-lane quarter reads the same 16 lds-rows (proven 0-conflict shape).
// =====================================================================
__global__ __launch_bounds__(512, 2) void gemm2_8p_kernel(
    const u16* __restrict__ A,
    const u16* __restrict__ B,
    float* __restrict__ C) {
  extern __shared__ char lds[];
  const long K = II;
  const int NT = (int)(K >> 6);
  const int tid = threadIdx.x;
  const int w = tid >> 6, l = tid & 63;
  const int l31 = l & 31, lhi = l >> 5;
  const int lr4 = l31 & 15, rb = (l31 >> 4) & 1;
  const int wm = w >> 2, wn = w & 3;
  const int lin = blockIdx.y * 16 + blockIdx.x;      // nwg=256
  const int xc = lin & 7, rr_ = lin >> 3;
  const long m0 = (long)((xc >> 1) * 4 + (rr_ & 3)) * 256;
  const long n0 = (long)((xc & 1) * 8 + (rr_ >> 2)) * 256;
  const int wb = w * 1024;

  // staging source pre-swizzle (inverse of read layout); dest stays linear
  const int ls_ = tid & 15, lr_ = (tid >> 4) & 15, h2_ = tid >> 8;
  const int sp_ = ls_ ^ lr_;
  const int srow = h2_ * 32 + (sp_ & 1) * 16 + lr_;
  const int skk  = (sp_ >> 1) * 8;
  const u16* sA00 = A + (m0 +       srow) * K + skk;
  const u16* sA01 = A + (m0 +  64 + srow) * K + skk;
  const u16* sA10 = A + (m0 + 128 + srow) * K + skk;
  const u16* sA11 = A + (m0 + 192 + srow) * K + skk;
  const u16* sB00 = B + (n0 +       srow) * K + skk;
  const u16* sB01 = B + (n0 +  64 + srow) * K + skk;
  const u16* sB10 = B + (n0 + 128 + srow) * K + skk;
  const u16* sB11 = B + (n0 + 192 + srow) * K + skk;

#define G2_STAGE_A0(bb, kt) do { \
    load_lds16(sA00 + (long)(kt) * 64, lds + (bb) + wb); \
    load_lds16(sA01 + (long)(kt) * 64, lds + (bb) + 8192 + wb); } while (0)
#define G2_STAGE_A1(bb, kt) do { \
    load_lds16(sA10 + (long)(kt) * 64, lds + (bb) + 16384 + wb); \
    load_lds16(sA11 + (long)(kt) * 64, lds + (bb) + 24576 + wb); } while (0)
#define G2_STAGE_B0(bb, kt) do { \
    load_lds16(sB00 + (long)(kt) * 64, lds + (bb) + 32768 + wb); \
    load_lds16(sB01 + (long)(kt) * 64, lds + (bb) + 40960 + wb); } while (0)
#define G2_STAGE_B1(bb, kt) do { \
    load_lds16(sB10 + (long)(kt) * 64, lds + (bb) + 49152 + wb); \
    load_lds16(sB11 + (long)(kt) * 64, lds + (bb) + 57344 + wb); } while (0)

  int aoffk[2][4], boffk[4];
#pragma unroll
  for (int bm = 0; bm < 2; ++bm)
#pragma unroll
    for (int ks = 0; ks < 4; ++ks) {
      int sp = ks * 4 + lhi * 2 + rb;
      aoffk[bm][ks] = wm * 8192 + bm * 4096 + lr4 * 256 + ((sp ^ lr4) * 16);
    }
#pragma unroll
  for (int ks = 0; ks < 4; ++ks) {
    int sp = ks * 4 + lhi * 2 + rb;
    boffk[ks] = wn * 4096 + lr4 * 256 + ((sp ^ lr4) * 16);
  }

  f32x16 acc[4][2];
#pragma unroll
  for (int t = 0; t < 4; ++t)
#pragma unroll
    for (int bn = 0; bn < 2; ++bn) acc[t][bn] = (f32x16)0.f;

  G2_STAGE_A0(0, 0); G2_STAGE_A1(0, 0); G2_STAGE_B0(0, 0); G2_STAGE_B1(0, 0);
  G2_STAGE_A0(65536, 1); G2_STAGE_B1(65536, 1); G2_STAGE_A1(65536, 1);
  WAIT_VM6();
  SBAR();

  bf16x8 af[2][4], b0v[4], b1v[4];
#pragma unroll
  for (int bm = 0; bm < 2; ++bm)
#pragma unroll
    for (int ks = 0; ks < 4; ++ks)
      af[bm][ks] = *(const bf16x8*)(lds + aoffk[bm][ks]);
#pragma unroll
  for (int ks = 0; ks < 4; ++ks)
    b0v[ks] = *(const bf16x8*)(lds + 32768 + boffk[ks]);

#define G2_MFMA(qm, qn, bset) do { \
    __builtin_amdgcn_s_setprio(1); \
    _Pragma("unroll") for (int ks = 0; ks < 4; ++ks) \
      _Pragma("unroll") for (int bm = 0; bm < 2; ++bm) \
        acc[(qm) * 2 + bm][qn] = __builtin_amdgcn_mfma_f32_32x32x16_bf16( \
            af[bm][ks], bset[ks], acc[(qm) * 2 + bm][qn], 0, 0, 0); \
    __builtin_amdgcn_s_setprio(0); } while (0)

  for (int kt = 0; kt < NT; ++kt) {
    const int bb = (kt & 1) << 16;
    const int ob = bb ^ 65536;
    const char* Lb = lds + bb;
#pragma unroll
    for (int ks = 0; ks < 4; ++ks)
      b1v[ks] = *(const bf16x8*)(Lb + 49152 + boffk[ks]);
    if (kt + 1 < NT) G2_STAGE_B0(ob, kt + 1);
    SBAR(); SCHED0();
    G2_MFMA(0, 0, b0v);
    SCHED0(); SBAR();
    if (kt + 2 < NT) G2_STAGE_A0(bb, kt + 2);
    SBAR(); SCHED0();
    G2_MFMA(0, 1, b1v);
    SCHED0();
#pragma unroll
    for (int bm = 0; bm < 2; ++bm)
#pragma unroll
      for (int ks = 0; ks < 4; ++ks)
        af[bm][ks] = *(const bf16x8*)(Lb + 16384 + aoffk[bm][ks]);
    SBAR();
    if (kt + 2 < NT) G2_STAGE_B1(bb, kt + 2);
    SBAR(); SCHED0();
    G2_MFMA(1, 1, b1v);
    SCHED0(); SBAR();
    if (kt + 2 < NT) G2_STAGE_A1(bb, kt + 2);
    SBAR(); SCHED0();
    G2_MFMA(1, 0, b0v);
    SCHED0();
    if (kt + 2 < NT) { WAIT_VM6(); } else { WAIT_VM0(); }
    SBAR();
    if (kt + 1 < NT) {
      const char* Lo = lds + ob;
#pragma unroll
      for (int bm = 0; bm < 2; ++bm)
#pragma unroll
        for (int ks = 0; ks < 4; ++ks)
          af[bm][ks] = *(const bf16x8*)(Lo + aoffk[bm][ks]);
#pragma unroll
      for (int ks = 0; ks < 4; ++ks)
        b0v[ks] = *(const bf16x8*)(Lo + 32768 + boffk[ks]);
    }
  }

#pragma unroll
  for (int t = 0; t < 4; ++t) {
    long mb = m0 + (t >> 1) * 128 + wm * 64 + (t & 1) * 32;
#pragma unroll
    for (int bn = 0; bn < 2; ++bn) {
      long col = n0 + bn * 128 + wn * 32 + l31;
#pragma unroll
      for (int r = 0; r < 16; ++r) {
        long m = mb + (r & 3) + 8 * (r >> 2) + 4 * lhi;
        C[m * HH + col] = acc[t][bn][r];
      }
    }
  }
#undef G2_STAGE_A0
#undef G2_STAGE_A1
#undef G2_STAGE_B0
#undef G2_STAGE_B1
#undef G2_MFMA
}

// =====================================================================
// GEMM1 fused: swiglu(X @ gup^T), 32x32x16, 4m x 8n bricks, tile-split
// gup pack (acc[t][0]=gate, acc[t][1]=up, same lane+reg), NEW LDS layout.
// Aux tail = dwb convert (aid<256) + adapter psum (aid>=256).
// =====================================================================
__global__ __launch_bounds__(512, 2) void gemm1_fused_kernel(
    const u16* __restrict__ A,     // xb [TT][HH]
    const u16* __restrict__ B,     // gup [2I][HH] tile-split packed
    u16* __restrict__ inter,       // [TT][II]
    int naux,
    const float* __restrict__ dww, u16* __restrict__ dwb,
    const u16* __restrict__ wab, float* __restrict__ psum,
    const int* __restrict__ cnt, const int* __restrict__ off,
    const int* __restrict__ list) {
  extern __shared__ char lds[];
  const int lin = blockIdx.x;
  const int tid = threadIdx.x;

  if (lin >= G1_NGEMM) {
    int aid = lin - G1_NGEMM;
    if (aid >= naux) return;
    if (aid < 256) {
      const long Q = HH * II / 4;
      long i = (long)aid * 512 + tid;
      for (; i < Q; i += 256L * 512)
        ((ushort4*)dwb)[i] = cvt4(((const float4*)dww)[i]);
    } else {
      int p = aid - 256;                     // [0, 2048)
      psum_body(lds, A, wab, cnt, off, list, psum,
                p & 7, (p >> 3) & 63, p >> 9, tid);
    }
    return;
  }

  // ---------------- GEMM path (4m x 8n brick mapping) ----------------
  const int xc = lin & 7, s = lin >> 3;     // s in [0,172)
  const int wv = s >> 5, rr_ = s & 31;
  const long m0 = (long)((xc >> 1) * 4 + (rr_ & 3)) * 256;
  const long n0 = (long)((xc & 1) * 43 + wv * 8 + (rr_ >> 2)) * 256;  // virtual

  const long K = HH;
  const int NT = (int)(K >> 6);             // 64
  const int w = tid >> 6, l = tid & 63;
  const int l31 = l & 31, lhi = l >> 5;
  const int lr4 = l31 & 15, rb = (l31 >> 4) & 1;
  const int wm = w >> 2, wn = w & 3;
  const int wb = w * 1024;

  const int ls_ = tid & 15, lr_ = (tid >> 4) & 15, h2_ = tid >> 8;
  const int sp_ = ls_ ^ lr_;
  const int srow = h2_ * 32 + (sp_ & 1) * 16 + lr_;
  const int skk  = (sp_ >> 1) * 8;
  const u16* sA00 = A + (m0 +       srow) * K + skk;
  const u16* sA01 = A + (m0 +  64 + srow) * K + skk;
  const u16* sA10 = A + (m0 + 128 + srow) * K + skk;
  const u16* sA11 = A + (m0 + 192 + srow) * K + skk;
  const u16* sB00 = B + (n0 +       srow) * K + skk;
  const u16* sB01 = B + (n0 +  64 + srow) * K + skk;
  const u16* sB10 = B + (n0 + 128 + srow) * K + skk;
  const u16* sB11 = B + (n0 + 192 + srow) * K + skk;

#define G1_STAGE_A0(bb, kt) do { \
    load_lds16(sA00 + (long)(kt) * 64, lds + (bb) + wb); \
    load_lds16(sA01 + (long)(kt) * 64, lds + (bb) + 8192 + wb); } while (0)
#define G1_STAGE_A1(bb, kt) do { \
    load_lds16(sA10 + (long)(kt) * 64, lds + (bb) + 16384 + wb); \
    load_lds16(sA11 + (long)(kt) * 64, lds + (bb) + 24576 + wb); } while (0)
#define G1_STAGE_B0(bb, kt) do { \
    load_lds16(sB00 + (long)(kt) * 64, lds + (bb) + 32768 + wb); \
    load_lds16(sB01 + (long)(kt) * 64, lds + (bb) + 40960 + wb); } while (0)
#define G1_STAGE_B1(bb, kt) do { \
    load_lds16(sB10 + (long)(kt) * 64, lds + (bb) + 49152 + wb); \
    load_lds16(sB11 + (long)(kt) * 64, lds + (bb) + 57344 + wb); } while (0)

  int aoffk[2][4], boffk[4];
#pragma unroll
  for (int bm = 0; bm < 2; ++bm)
#pragma unroll
    for (int ks = 0; ks < 4; ++ks) {
      int sp = ks * 4 + lhi * 2 + rb;
      aoffk[bm][ks] = wm * 8192 + bm * 4096 + lr4 * 256 + ((sp ^ lr4) * 16);
    }
#pragma unroll
  for (int ks = 0; ks < 4; ++ks) {
    int sp = ks * 4 + lhi * 2 + rb;
    boffk[ks] = wn * 4096 + lr4 * 256 + ((sp ^ lr4) * 16);
  }

  f32x16 acc[4][2];
#pragma unroll
  for (int t = 0; t < 4; ++t)
#pragma unroll
    for (int bn = 0; bn < 2; ++bn) acc[t][bn] = (f32x16)0.f;

  G1_STAGE_A0(0, 0); G1_STAGE_A1(0, 0); G1_STAGE_B0(0, 0); G1_STAGE_B1(0, 0);
  G1_STAGE_A0(65536, 1); G1_STAGE_B1(65536, 1); G1_STAGE_A1(65536, 1);
  WAIT_VM6();
  SBAR();

  bf16x8 af[2][4], b0v[4], b1v[4];
#pragma unroll
  for (int bm = 0; bm < 2; ++bm)
#pragma unroll
    for (int ks = 0; ks < 4; ++ks)
      af[bm][ks] = *(const bf16x8*)(lds + aoffk[bm][ks]);
#pragma unroll
  for (int ks = 0; ks < 4; ++ks)
    b0v[ks] = *(const bf16x8*)(lds + 32768 + boffk[ks]);

#define G1_MFMA(qm, qn, bset) do { \
    __builtin_amdgcn_s_setprio(1); \
    _Pragma("unroll") for (int ks = 0; ks < 4; ++ks) \
      _Pragma("unroll") for (int bm = 0; bm < 2; ++bm) \
        acc[(qm) * 2 + bm][qn] = __builtin_amdgcn_mfma_f32_32x32x16_bf16( \
            af[bm][ks], bset[ks], acc[(qm) * 2 + bm][qn], 0, 0, 0); \
    __builtin_amdgcn_s_setprio(0); } while (0)

  for (int kt = 0; kt < NT; ++kt) {
    const int bb = (kt & 1) << 16;
    const int ob = bb ^ 65536;
    const char* Lb = lds + bb;
#pragma unroll
    for (int ks = 0; ks < 4; ++ks)
      b1v[ks] = *(const bf16x8*)(Lb + 49152 + boffk[ks]);
    if (kt + 1 < NT) G1_STAGE_B0(ob, kt + 1);
    SBAR(); SCHED0();
    G1_MFMA(0, 0, b0v);
    SCHED0(); SBAR();
    if (kt + 2 < NT) G1_STAGE_A0(bb, kt + 2);
    SBAR(); SCHED0();
    G1_MFMA(0, 1, b1v);
    SCHED0();
#pragma unroll
    for (int bm = 0; bm < 2; ++bm)
#pragma unroll
      for (int ks = 0; ks < 4; ++ks)
        af[bm][ks] = *(const bf16x8*)(Lb + 16384 + aoffk[bm][ks]);
    SBAR();
    if (kt + 2 < NT) G1_STAGE_B1(bb, kt + 2);
    SBAR(); SCHED0();
    G1_MFMA(1, 1, b1v);
    SCHED0(); SBAR();
    if (kt + 2 < NT) G1_STAGE_A1(bb, kt + 2);
    SBAR(); SCHED0();
    G1_MFMA(1, 0, b0v);
    SCHED0();
    if (kt + 2 < NT) { WAIT_VM6(); } else { WAIT_VM0(); }
    SBAR();
    if (kt + 1 < NT) {
      const char* Lo = lds + ob;
#pragma unroll
      for (int bm = 0; bm < 2; ++bm)
#pragma unroll
        for (int ks = 0; ks < 4; ++ks)
          af[bm][ks] = *(const bf16x8*)(Lo + aoffk[bm][ks]);
#pragma unroll
      for (int ks = 0; ks < 4; ++ks)
        b0v[ks] = *(const bf16x8*)(Lo + 32768 + boffk[ks]);
    }
  }

  // epilogue: acc[t][0]=gate, acc[t][1]=up for inter col ic (same lane/reg).
  {
    const long ic = (n0 >> 1) + wn * 32 + l31;
#pragma unroll
    for (int t = 0; t < 4; ++t) {
      long mb = m0 + (t >> 1) * 128 + wm * 64 + (t & 1) * 32;
#pragma unroll
      for (int r = 0; r < 16; ++r) {
        float g = acc[t][0][r], u = acc[t][1][r];
        float sv = g / (1.f + __expf(-g));
        long m = mb + (r & 3) + 8 * (r >> 2) + 4 * lhi;
        inter[m * II + ic] = f2bf(sv * u);
      }
    }
  }
#undef G1_STAGE_A0
#undef G1_STAGE_A1
#undef G1_STAGE_B0
#undef G1_STAGE_B1
#undef G1_MFMA
}

// ---------- launcher ----------
extern "C" void kernel_launch(void* const* d_in, const int* in_sizes, int n_in,
                              void* d_out, int out_size, void* d_ws, size_t ws_size,
                              hipStream_t stream) {
  const float* x   = (const float*)d_in[0];
  const float* guw = (const float*)d_in[1];
  const float* dww = (const float*)d_in[2];
  const float* rg  = (const float*)d_in[3];
  const float* ru  = (const float*)d_in[4];
  const float* rd  = (const float*)d_in[5];
  const float* fg  = (const float*)d_in[6];
  const float* fu  = (const float*)d_in[7];
  const float* fd  = (const float*)d_in[8];
  const float* sc  = (const float*)d_in[9];
  const int*   tix = (const int*)d_in[10];
  float* out = (float*)d_out;
  char* ws = (char*)d_ws;

  size_t o = 0;
  u16* xb            = (u16*)(ws + o); o += (size_t)TT * HH * 2;
  u16* gup           = (u16*)(ws + o); o += (size_t)2 * II * HH * 2;
  u16* dwb           = (u16*)(ws + o); o += (size_t)HH * II * 2;
  char* inter_base   = ws + o;         o += (size_t)TT * II * 2;
  u16* inter         = (u16*)inter_base;
  u16* wdb           = (u16*)(ws + o); o += (size_t)8 * HH * 128 * 2;
  u16* irb           = (u16*)(ws + o); o += (size_t)TT * 128 * 2;
  int* cntp          = (int*)(ws + o); o += 256;
  int* offp          = (int*)(ws + o); o += 256;
  int* listp         = (int*)(ws + o); o += (size_t)TT * 4;
  size_t o_shared = o;
  u16* wabA          = (u16*)(ws + o_shared);
  float* psumA       = (float*)(ws + o_shared + 16777216);
  size_t needA = o_shared + 16777216 + (size_t)4 * TT * 256 * 4;
  u16* wabB          = (u16*)inter_base;
  float* psumB       = (float*)(inter_base + 16777216);
  bool pathA = ws_size >= needA;
  u16* wab  = pathA ? wabA  : wabB;
  float* psum = pathA ? psumA : psumB;

  hipFuncSetAttribute((const void*)gemm1_fused_kernel,
                      hipFuncAttributeMaxDynamicSharedMemorySize, 131072);
  hipFuncSetAttribute((const void*)gemm2_8p_kernel,
                      hipFuncAttributeMaxDynamicSharedMemorySize, 131072);
  hipFuncSetAttribute((const void*)adapter_psum_kernel,
                      hipFuncAttributeMaxDynamicSharedMemorySize, 82176);
  hipFuncSetAttribute((const void*)adapter_down2_kernel,
                      hipFuncAttributeMaxDynamicSharedMemorySize, 81920);

  cvt_all_kernel<<<2433, 256, 0, stream>>>(
      x, xb, guw, gup, tix, cntp, offp, listp,
      rg, ru, fg, fu, wab, rd, fd, wdb);

  if (pathA) {
    gemm1_fused_kernel<<<G1_NGEMM + G1_NAUX, 512, 131072, stream>>>(
        xb, gup, inter, G1_NAUX, dww, dwb, wab, psum, cntp, offp, listp);
    adapter_reduce_kernel<<<2048, 256, 0, stream>>>(psum, sc, tix, irb);
  } else {
    adapter_psum_kernel<<<dim3(NSLOT, 64, 4), 512, 82176, stream>>>(
        xb, wab, cntp, offp, listp, psum);
    gemm1_fused_kernel<<<G1_NGEMM + 256, 512, 131072, stream>>>(
        xb, gup, inter, 256, dww, dwb, wab, psum, cntp, offp, listp);
    adapter_reduce_kernel<<<2048, 256, 0, stream>>>(psum, sc, tix, irb);
  }

  gemm2_8p_kernel<<<dim3(16, 16), 512, 131072, stream>>>(inter, dwb, out);
  adapter_down2_kernel<<<dim3(NSLOT, 64, 16), 512, 81920, stream>>>(
      irb, wdb, cntp, offp, listp, out);
}

// Round 14
// 1122.505 us; speedup vs baseline: 1.1476x; 1.0815x over previous
//
#include <hip/hip_runtime.h>
#include <hip/hip_bf16.h>

#define TT 4096L
#define HH 4096L
#define II 11008L
#define NSLOT 8

typedef short bf16x8 __attribute__((ext_vector_type(8)));
typedef float f32x4  __attribute__((ext_vector_type(4)));

#define WAIT_VM6() asm volatile("s_waitcnt vmcnt(6)" ::: "memory")
#define WAIT_VM0() asm volatile("s_waitcnt vmcnt(0)" ::: "memory")
#define SBAR() __builtin_amdgcn_s_barrier()
#define SCHED0() __builtin_amdgcn_sched_barrier(0)

#define G1_NGEMM 1376   // 16 m-tiles x 86 n-tiles, 4m x 8n XCD bricks
#define G1_NAUX  2304   // 256 dwb-cvt blocks + 2048 psum blocks

typedef unsigned short u16;

__device__ __forceinline__ u16 f2bf(float v) {
  union { float f; unsigned int u; } c; c.f = v;
  unsigned int u = c.u;
  u += 0x7fffu + ((u >> 16) & 1u);
  return (u16)(u >> 16);
}

__device__ __forceinline__ void load_lds16(const void* g, void* lds) {
  __builtin_amdgcn_global_load_lds(
      (const __attribute__((address_space(1))) unsigned int*)g,
      (__attribute__((address_space(3))) unsigned int*)lds, 16, 0, 0);
}

__device__ __forceinline__ ushort4 cvt4(float4 v) {
  ushort4 o;
  o.x = f2bf(v.x); o.y = f2bf(v.y); o.z = f2bf(v.z); o.w = f2bf(v.w);
  return o;
}

// ---------- fused convert: xb (plain) + gup (paired pack) ----------
__global__ __launch_bounds__(256) void cvt_xgup_kernel(
    const float* __restrict__ x, u16* __restrict__ xb,
    const float* __restrict__ guw, u16* __restrict__ gup) {
  const long NX = TT * HH / 4;
  const long NG = 2L * II * HH / 4;
  long i = (long)blockIdx.x * blockDim.x + threadIdx.x;
  long stride = (long)gridDim.x * blockDim.x;
  for (; i < NX + NG; i += stride) {
    if (i < NX) {
      ((ushort4*)xb)[i] = cvt4(((const float4*)x)[i]);
    } else {
      long g = i - NX;
      long grow = g >> 10;
      long q = g & 1023;
      long c16 = grow >> 5;
      int r = (int)(grow & 31);
      long src = (r < 16) ? (c16 * 16 + r) : (II + c16 * 16 + (r - 16));
      ((ushort4*)gup)[g] = cvt4(((const float4*)guw)[src * 1024 + q]);
    }
  }
}

// ---------- prep: bucket (block 0) + wab cvt (1..256) + wdb cvt (257..384) ----------
__global__ __launch_bounds__(256) void prep_kernel(
    const int* __restrict__ tix, int* __restrict__ cnt,
    int* __restrict__ off, int* __restrict__ list,
    const float* __restrict__ rg, const float* __restrict__ ru,
    const float* __restrict__ fg, const float* __restrict__ fu,
    u16* __restrict__ wab,
    const float* __restrict__ rd, const float* __restrict__ fd,
    u16* __restrict__ wdb) {
  int bid = blockIdx.x;
  int tid = threadIdx.x;
  if (bid == 0) {
    __shared__ int lc[NSLOT], lo[NSLOT], pc[NSLOT];
    if (tid < NSLOT) { lc[tid] = 0; pc[tid] = 0; }
    __syncthreads();
    for (int t = tid; t < TT; t += 256) atomicAdd(&lc[tix[t]], 1);
    __syncthreads();
    if (tid == 0) {
      int s = 0;
      for (int i = 0; i < NSLOT; ++i) { lo[i] = s; s += lc[i]; }
    }
    __syncthreads();
    for (int t = tid; t < TT; t += 256) {
      int s = tix[t];
      int p = atomicAdd(&pc[s], 1);
      list[lo[s] + p] = t;
    }
    if (tid < NSLOT) { cnt[tid] = lc[tid]; off[tid] = lo[tid]; }
  } else if (bid <= 256) {
    const long Q = 8L * 256 * HH / 4;
    long i = (long)(bid - 1) * 256 + tid;
    for (; i < Q; i += 256L * 256) {
      long grow = i >> 10, q = i & 1023;
      int s = (int)(grow >> 8), r = (int)(grow & 255);
      const float* src;
      int rr = r & 63;
      if (r < 64) src = rg; else if (r < 128) src = ru;
      else if (r < 192) src = fg; else src = fu;
      ((ushort4*)wab)[i] = cvt4(((const float4*)src)[((long)s * 64 + rr) * 1024 + q]);
    }
  } else {
    const long Q = 8L * HH * 128 / 4;
    long i = (long)(bid - 257) * 256 + tid;
    for (; i < Q; i += 128L * 256) {
      long rowg = i >> 5;
      int q = (int)(i & 31);
      float4 v = (q < 16) ? ((const float4*)rd)[rowg * 16 + q]
                          : ((const float4*)fd)[rowg * 16 + (q - 16)];
      ((ushort4*)wdb)[i] = cvt4(v);
    }
  }
}

// =====================================================================
// Adapter phase 1 body (MFMA, split-K=4) — shared by standalone + aux.
// =====================================================================
__device__ __forceinline__ void psum_body(
    char* lds, const u16* __restrict__ xb, const u16* __restrict__ wab,
    const int* __restrict__ cnt, const int* __restrict__ off,
    const int* __restrict__ list, float* __restrict__ psum,
    int s, int c, int kq, int tid) {
  int n = cnt[s];
  if (c * 64 >= n) return;
  int* tl = (int*)(lds + 81920);
  int base = off[s] + c * 64;
  int ntok = min(64, n - c * 64);
  if (tid < 64) tl[tid] = (tid < ntok) ? list[base + tid] : list[base];
  __syncthreads();
  const int w = tid >> 6, l = tid & 63, l16 = l & 15, lq = l >> 4;
  const int sslot = (tid & 7) ^ ((tid >> 3) & 7);
  const long kbase = (long)kq * 1024;
  const u16* xsrc = xb + (size_t)tl[tid >> 3] * HH + kbase + sslot * 8;
  const u16* wsrc = wab + ((size_t)s * 256 + (tid >> 3)) * HH + kbase + sslot * 8;
  const int wdst = w * 1024;

#define PS_STAGE(buf, t) do { \
    load_lds16(xsrc + (long)(t) * 64, lds + (buf) + wdst); \
    _Pragma("unroll") for (int r = 0; r < 4; ++r) \
      load_lds16(wsrc + (size_t)(r * 64) * HH + (long)(t) * 64, \
                 lds + (buf) + 8192 + r * 8192 + wdst); } while (0)

  const int sw = l16 & 7;
  f32x4 acc[4][2];
#pragma unroll
  for (int i = 0; i < 4; ++i)
#pragma unroll
    for (int j = 0; j < 2; ++j) acc[i][j] = (f32x4)0.f;

  PS_STAGE(0, 0);
  __syncthreads();
  for (int t = 0; t < 16; ++t) {
    const int cb = (t & 1) * 40960;
    if (t + 1 < 16) PS_STAGE(cb ^ 40960, t + 1);
    const char* Lb = lds + cb;
    bf16x8 av[4][2], bv[2][2];
#pragma unroll
    for (int i = 0; i < 4; ++i)
#pragma unroll
      for (int kh = 0; kh < 2; ++kh)
        av[i][kh] = *(const bf16x8*)(Lb + (i * 16 + l16) * 128 + (((kh * 4 + lq) ^ sw) * 16));
#pragma unroll
    for (int j = 0; j < 2; ++j)
#pragma unroll
      for (int kh = 0; kh < 2; ++kh)
        bv[j][kh] = *(const bf16x8*)(Lb + 8192 + (w * 32 + j * 16 + l16) * 128 + (((kh * 4 + lq) ^ sw) * 16));
#pragma unroll
    for (int i = 0; i < 4; ++i)
#pragma unroll
      for (int j = 0; j < 2; ++j) {
        acc[i][j] = __builtin_amdgcn_mfma_f32_16x16x32_bf16(av[i][0], bv[j][0], acc[i][j], 0, 0, 0);
        acc[i][j] = __builtin_amdgcn_mfma_f32_16x16x32_bf16(av[i][1], bv[j][1], acc[i][j], 0, 0, 0);
      }
    __syncthreads();
  }
  float* pb = psum + (size_t)kq * TT * 256;
#pragma unroll
  for (int i = 0; i < 4; ++i)
#pragma unroll
    for (int j = 0; j < 2; ++j)
#pragma unroll
      for (int r = 0; r < 4; ++r) {
        int tk = i * 16 + lq * 4 + r;
        pb[(size_t)tl[tk] * 256 + w * 32 + j * 16 + l16] = acc[i][j][r];
      }
#undef PS_STAGE
}

// standalone psum (path B)
__global__ __launch_bounds__(512) void adapter_psum_kernel(
    const u16* __restrict__ xb, const u16* __restrict__ wab,
    const int* __restrict__ cnt, const int* __restrict__ off,
    const int* __restrict__ list, float* __restrict__ psum) {
  extern __shared__ char lds[];
  psum_body(lds, xb, wab, cnt, off, list, psum,
            blockIdx.x, blockIdx.y, blockIdx.z, threadIdx.x);
}

// ---------- reduce split-K + SwiGLU + scale -> irb bf16 [T][128] ----------
__global__ __launch_bounds__(256) void adapter_reduce_kernel(
    const float* __restrict__ psum, const float* __restrict__ scales,
    const int* __restrict__ tix, u16* __restrict__ irb) {
  int idx = blockIdx.x * 256 + threadIdx.x;
  int t = idx >> 7, n = idx & 127;
  int a = n >> 6, nn = n & 63;
  int cg = a ? 128 + nn : nn;
  size_t b = (size_t)t * 256;
  float g = 0.f, u = 0.f;
#pragma unroll
  for (int kq = 0; kq < 4; ++kq) {
    g += psum[(size_t)kq * TT * 256 + b + cg];
    u += psum[(size_t)kq * TT * 256 + b + cg + 64];
  }
  float sc = scales[tix[t] * 2 + a];
  float sv = g / (1.f + __expf(-g));
  irb[idx] = f2bf(sv * u * sc);
}

// =====================================================================
// Adapter phase 2 (MFMA): out[t][h] += irb[t][:] @ wdb[s][h][:]^T
// =====================================================================
__global__ __launch_bounds__(512) void adapter_down2_kernel(
    const u16* __restrict__ irb, const u16* __restrict__ wdb,
    const int* __restrict__ cnt, const int* __restrict__ off,
    const int* __restrict__ list, float* __restrict__ out) {
  extern __shared__ char lds[];
  __shared__ int tl[64];
  int s = blockIdx.x, c = blockIdx.y, hb = blockIdx.z;
  int n = cnt[s];
  if (c * 64 >= n) return;
  int base = off[s] + c * 64;
  int ntok = min(64, n - c * 64);
  int tid = threadIdx.x;
  if (tid < 64) tl[tid] = (tid < ntok) ? list[base + tid] : list[base];
  __syncthreads();
  const int w = tid >> 6, l = tid & 63, l16 = l & 15, lq = l >> 4;
  const int sslot = (tid & 15) ^ ((tid >> 4) & 15);
  const int wdst = w * 1024;
  const u16* isrc0 = irb + (size_t)tl[tid >> 4] * 128 + sslot * 8;
  const u16* isrc1 = irb + (size_t)tl[32 + (tid >> 4)] * 128 + sslot * 8;
  const u16* wsrc =
      wdb + ((size_t)s * HH + hb * 256 + (tid >> 4)) * 128 + sslot * 8;
  load_lds16(isrc0, lds + wdst);
  load_lds16(isrc1, lds + 8192 + wdst);
#pragma unroll
  for (int r = 0; r < 8; ++r)
    load_lds16(wsrc + (size_t)r * 4096, lds + 16384 + r * 8192 + wdst);
  __syncthreads();

  f32x4 acc[4][2];
#pragma unroll
  for (int i = 0; i < 4; ++i)
#pragma unroll
    for (int j = 0; j < 2; ++j) acc[i][j] = (f32x4)0.f;

#pragma unroll
  for (int kf = 0; kf < 4; ++kf) {
    bf16x8 av[4], bv[2];
#pragma unroll
    for (int i = 0; i < 4; ++i)
      av[i] = *(const bf16x8*)(lds + (i * 16 + l16) * 256 + (((kf * 4 + lq) ^ l16) * 16));
#pragma unroll
    for (int j = 0; j < 2; ++j)
      bv[j] = *(const bf16x8*)(lds + 16384 + (w * 32 + j * 16 + l16) * 256 + (((kf * 4 + lq) ^ l16) * 16));
#pragma unroll
    for (int i = 0; i < 4; ++i)
#pragma unroll
      for (int j = 0; j < 2; ++j)
        acc[i][j] = __builtin_amdgcn_mfma_f32_16x16x32_bf16(av[i], bv[j], acc[i][j], 0, 0, 0);
  }
#pragma unroll
  for (int i = 0; i < 4; ++i)
#pragma unroll
    for (int j = 0; j < 2; ++j)
#pragma unroll
      for (int r = 0; r < 4; ++r) {
        int tk = i * 16 + lq * 4 + r;
        if (tk < ntok) {
          size_t o = (size_t)tl[tk] * HH + hb * 256 + w * 32 + j * 16 + l16;
          out[o] += acc[i][j][r];
        }
      }
}

// =====================================================================
// GEMM2: C = inter @ down_w^T — 256x256, BK=64, 8-phase staggered frags,
// 4m x 8n XCD-brick mapping, 16x16x32 MFMA (round-10 best config).
// =====================================================================
__global__ __launch_bounds__(512, 2) void gemm2_8p_kernel(
    const u16* __restrict__ A,
    const u16* __restrict__ B,
    float* __restrict__ C) {
  extern __shared__ char lds[];
  const long K = II;
  const int NT = (int)(K >> 6);
  const int tid = threadIdx.x;
  const int w = tid >> 6, l = tid & 63, l16 = l & 15, lq = l >> 4;
  const int wm = w >> 2, wn = w & 3;
  const int lin = blockIdx.y * 16 + blockIdx.x;      // nwg=256
  const int xc = lin & 7, rr_ = lin >> 3;            // rr_ in [0,32)
  const long m0 = (long)((xc >> 1) * 4 + (rr_ & 3)) * 256;
  const long n0 = (long)((xc & 1) * 8 + (rr_ >> 2)) * 256;
  const int wb = w * 1024;

  const int srow = tid >> 3;
  const int sslot = (tid & 7) ^ (srow & 7);
  const u16* sA00 = A + (m0 +       srow) * K + sslot * 8;
  const u16* sA01 = A + (m0 +  64 + srow) * K + sslot * 8;
  const u16* sA10 = A + (m0 + 128 + srow) * K + sslot * 8;
  const u16* sA11 = A + (m0 + 192 + srow) * K + sslot * 8;
  const u16* sB00 = B + (n0 +       srow) * K + sslot * 8;
  const u16* sB01 = B + (n0 +  64 + srow) * K + sslot * 8;
  const u16* sB10 = B + (n0 + 128 + srow) * K + sslot * 8;
  const u16* sB11 = B + (n0 + 192 + srow) * K + sslot * 8;

#define G2_STAGE_A0(bb, kt) do { \
    load_lds16(sA00 + (long)(kt) * 64, lds + (bb) + wb); \
    load_lds16(sA01 + (long)(kt) * 64, lds + (bb) + 8192 + wb); } while (0)
#define G2_STAGE_A1(bb, kt) do { \
    load_lds16(sA10 + (long)(kt) * 64, lds + (bb) + 16384 + wb); \
    load_lds16(sA11 + (long)(kt) * 64, lds + (bb) + 24576 + wb); } while (0)
#define G2_STAGE_B0(bb, kt) do { \
    load_lds16(sB00 + (long)(kt) * 64, lds + (bb) + 32768 + wb); \
    load_lds16(sB01 + (long)(kt) * 64, lds + (bb) + 40960 + wb); } while (0)
#define G2_STAGE_B1(bb, kt) do { \
    load_lds16(sB10 + (long)(kt) * 64, lds + (bb) + 49152 + wb); \
    load_lds16(sB11 + (long)(kt) * 64, lds + (bb) + 57344 + wb); } while (0)

  const int sw = l16 & 7;
  const int aoff0 = (wm * 64 + l16) * 128 + ((0 + lq) ^ sw) * 16;
  const int aoff1 = (wm * 64 + l16) * 128 + ((4 + lq) ^ sw) * 16;
  const int boff0 = (wn * 32 + l16) * 128 + ((0 + lq) ^ sw) * 16;
  const int boff1 = (wn * 32 + l16) * 128 + ((4 + lq) ^ sw) * 16;

  f32x4 acc[2][2][4][2];
#pragma unroll
  for (int qm = 0; qm < 2; ++qm)
#pragma unroll
    for (int qn = 0; qn < 2; ++qn)
#pragma unroll
      for (int i = 0; i < 4; ++i)
#pragma unroll
        for (int j = 0; j < 2; ++j) acc[qm][qn][i][j] = (f32x4)0.f;

  G2_STAGE_A0(0, 0); G2_STAGE_A1(0, 0); G2_STAGE_B0(0, 0); G2_STAGE_B1(0, 0);
  G2_STAGE_A0(65536, 1); G2_STAGE_B1(65536, 1); G2_STAGE_A1(65536, 1);
  WAIT_VM6();
  SBAR();

  bf16x8 af[4][2], b0v[2][2], b1v[2][2];
#pragma unroll
  for (int i = 0; i < 4; ++i) {
    af[i][0] = *(const bf16x8*)(lds + aoff0 + i * 2048);
    af[i][1] = *(const bf16x8*)(lds + aoff1 + i * 2048);
  }
#pragma unroll
  for (int j = 0; j < 2; ++j) {
    b0v[j][0] = *(const bf16x8*)(lds + 32768 + boff0 + j * 2048);
    b0v[j][1] = *(const bf16x8*)(lds + 32768 + boff1 + j * 2048);
  }

#define G2_MFMA(qm, qn, bset) do { \
    __builtin_amdgcn_s_setprio(1); \
    _Pragma("unroll") for (int i = 0; i < 4; ++i) \
      _Pragma("unroll") for (int j = 0; j < 2; ++j) { \
        acc[qm][qn][i][j] = __builtin_amdgcn_mfma_f32_16x16x32_bf16(af[i][0], bset[j][0], acc[qm][qn][i][j], 0, 0, 0); \
        acc[qm][qn][i][j] = __builtin_amdgcn_mfma_f32_16x16x32_bf16(af[i][1], bset[j][1], acc[qm][qn][i][j], 0, 0, 0); } \
    __builtin_amdgcn_s_setprio(0); } while (0)

  for (int kt = 0; kt < NT; ++kt) {
    const int bb = (kt & 1) << 16;
    const int ob = bb ^ 65536;
    const char* Lb = lds + bb;
#pragma unroll
    for (int j = 0; j < 2; ++j) {
      b1v[j][0] = *(const bf16x8*)(Lb + 49152 + boff0 + j * 2048);
      b1v[j][1] = *(const bf16x8*)(Lb + 49152 + boff1 + j * 2048);
    }
    if (kt + 1 < NT) G2_STAGE_B0(ob, kt + 1);
    SBAR(); SCHED0();
    G2_MFMA(0, 0, b0v);
    SCHED0(); SBAR();
    if (kt + 2 < NT) G2_STAGE_A0(bb, kt + 2);
    SBAR(); SCHED0();
    G2_MFMA(0, 1, b1v);
    SCHED0();
#pragma unroll
    for (int i = 0; i < 4; ++i) {
      af[i][0] = *(const bf16x8*)(Lb + 16384 + aoff0 + i * 2048);
      af[i][1] = *(const bf16x8*)(Lb + 16384 + aoff1 + i * 2048);
    }
    SBAR();
    if (kt + 2 < NT) G2_STAGE_B1(bb, kt + 2);
    SBAR(); SCHED0();
    G2_MFMA(1, 1, b1v);
    SCHED0(); SBAR();
    if (kt + 2 < NT) G2_STAGE_A1(bb, kt + 2);
    SBAR(); SCHED0();
    G2_MFMA(1, 0, b0v);
    SCHED0();
    if (kt + 2 < NT) { WAIT_VM6(); } else { WAIT_VM0(); }
    SBAR();
    if (kt + 1 < NT) {
      const char* Lo = lds + ob;
#pragma unroll
      for (int i = 0; i < 4; ++i) {
        af[i][0] = *(const bf16x8*)(Lo + aoff0 + i * 2048);
        af[i][1] = *(const bf16x8*)(Lo + aoff1 + i * 2048);
      }
#pragma unroll
      for (int j = 0; j < 2; ++j) {
        b0v[j][0] = *(const bf16x8*)(Lo + 32768 + boff0 + j * 2048);
        b0v[j][1] = *(const bf16x8*)(Lo + 32768 + boff1 + j * 2048);
      }
    }
  }

#pragma unroll
  for (int qm = 0; qm < 2; ++qm)
#pragma unroll
    for (int qn = 0; qn < 2; ++qn)
#pragma unroll
      for (int i = 0; i < 4; ++i)
#pragma unroll
        for (int j = 0; j < 2; ++j)
#pragma unroll
          for (int r = 0; r < 4; ++r) {
            long m = m0 + qm * 128 + wm * 64 + i * 16 + lq * 4 + r;
            long nn = n0 + qn * 128 + wn * 32 + j * 16 + l16;
            C[m * HH + nn] = acc[qm][qn][i][j][r];
          }
#undef G2_STAGE_A0
#undef G2_STAGE_A1
#undef G2_STAGE_B0
#undef G2_STAGE_B1
#undef G2_MFMA
}

// =====================================================================
// GEMM1 fused: swiglu(X @ gup^T), 8-phase staggered frags, 4m x 8n
// XCD-brick mapping; aux tail = dwb convert (aid<256) + psum (aid>=256).
// =====================================================================
__global__ __launch_bounds__(512, 2) void gemm1_fused_kernel(
    const u16* __restrict__ A,     // xb [TT][HH]
    const u16* __restrict__ B,     // gup [2I][HH] paired
    u16* __restrict__ inter,       // [TT][II]
    int naux,
    const float* __restrict__ dww, u16* __restrict__ dwb,
    const u16* __restrict__ wab, float* __restrict__ psum,
    const int* __restrict__ cnt, const int* __restrict__ off,
    const int* __restrict__ list) {
  extern __shared__ char lds[];
  const int lin = blockIdx.x;
  const int tid = threadIdx.x;

  if (lin >= G1_NGEMM) {
    int aid = lin - G1_NGEMM;
    if (aid >= naux) return;
    if (aid < 256) {
      const long Q = HH * II / 4;
      long i = (long)aid * 512 + tid;
      for (; i < Q; i += 256L * 512)
        ((ushort4*)dwb)[i] = cvt4(((const float4*)dww)[i]);
    } else {
      int p = aid - 256;                     // [0, 2048)
      psum_body(lds, A, wab, cnt, off, list, psum,
                p & 7, (p >> 3) & 63, p >> 9, tid);
    }
    return;
  }

  // ---------------- GEMM path (4m x 8n brick mapping) ----------------
  const int xc = lin & 7, s = lin >> 3;     // s in [0,172)
  const int wv = s >> 5, rr_ = s & 31;      // wv in [0,6); wv==5 has rr_<12
  const long m0 = (long)((xc >> 1) * 4 + (rr_ & 3)) * 256;
  const long n0 = (long)((xc & 1) * 43 + wv * 8 + (rr_ >> 2)) * 256;  // virtual

  const long K = HH;
  const int NT = (int)(K >> 6);             // 64
  const int w = tid >> 6, l = tid & 63, l16 = l & 15, lq = l >> 4;
  const int wm = w >> 2, wn = w & 3;
  const int wb = w * 1024;

  const int srow = tid >> 3;
  const int sslot = (tid & 7) ^ (srow & 7);
  const u16* sA00 = A + (m0 +       srow) * K + sslot * 8;
  const u16* sA01 = A + (m0 +  64 + srow) * K + sslot * 8;
  const u16* sA10 = A + (m0 + 128 + srow) * K + sslot * 8;
  const u16* sA11 = A + (m0 + 192 + srow) * K + sslot * 8;
  const u16* sB00 = B + (n0 +       srow) * K + sslot * 8;
  const u16* sB01 = B + (n0 +  64 + srow) * K + sslot * 8;
  const u16* sB10 = B + (n0 + 128 + srow) * K + sslot * 8;
  const u16* sB11 = B + (n0 + 192 + srow) * K + sslot * 8;

#define G1_STAGE_A0(bb, kt) do { \
    load_lds16(sA00 + (long)(kt) * 64, lds + (bb) + wb); \
    load_lds16(sA01 + (long)(kt) * 64, lds + (bb) + 8192 + wb); } while (0)
#define G1_STAGE_A1(bb, kt) do { \
    load_lds16(sA10 + (long)(kt) * 64, lds + (bb) + 16384 + wb); \
    load_lds16(sA11 + (long)(kt) * 64, lds + (bb) + 24576 + wb); } while (0)
#define G1_STAGE_B0(bb, kt) do { \
    load_lds16(sB00 + (long)(kt) * 64, lds + (bb) + 32768 + wb); \
    load_lds16(sB01 + (long)(kt) * 64, lds + (bb) + 40960 + wb); } while (0)
#define G1_STAGE_B1(bb, kt) do { \
    load_lds16(sB10 + (long)(kt) * 64, lds + (bb) + 49152 + wb); \
    load_lds16(sB11 + (long)(kt) * 64, lds + (bb) + 57344 + wb); } while (0)

  const int sw = l16 & 7;
  const int aoff0 = (wm * 64 + l16) * 128 + ((0 + lq) ^ sw) * 16;
  const int aoff1 = (wm * 64 + l16) * 128 + ((4 + lq) ^ sw) * 16;
  const int boff0 = (wn * 32 + l16) * 128 + ((0 + lq) ^ sw) * 16;
  const int boff1 = (wn * 32 + l16) * 128 + ((4 + lq) ^ sw) * 16;

  f32x4 acc[2][2][4][2];
#pragma unroll
  for (int qm = 0; qm < 2; ++qm)
#pragma unroll
    for (int qn = 0; qn < 2; ++qn)
#pragma unroll
      for (int i = 0; i < 4; ++i)
#pragma unroll
        for (int j = 0; j < 2; ++j) acc[qm][qn][i][j] = (f32x4)0.f;

  G1_STAGE_A0(0, 0); G1_STAGE_A1(0, 0); G1_STAGE_B0(0, 0); G1_STAGE_B1(0, 0);
  G1_STAGE_A0(65536, 1); G1_STAGE_B1(65536, 1); G1_STAGE_A1(65536, 1);
  WAIT_VM6();
  SBAR();

  bf16x8 af[4][2], b0v[2][2], b1v[2][2];
#pragma unroll
  for (int i = 0; i < 4; ++i) {
    af[i][0] = *(const bf16x8*)(lds + aoff0 + i * 2048);
    af[i][1] = *(const bf16x8*)(lds + aoff1 + i * 2048);
  }
#pragma unroll
  for (int j = 0; j < 2; ++j) {
    b0v[j][0] = *(const bf16x8*)(lds + 32768 + boff0 + j * 2048);
    b0v[j][1] = *(const bf16x8*)(lds + 32768 + boff1 + j * 2048);
  }

#define G1_MFMA(qm, qn, bset) do { \
    __builtin_amdgcn_s_setprio(1); \
    _Pragma("unroll") for (int i = 0; i < 4; ++i) \
      _Pragma("unroll") for (int j = 0; j < 2; ++j) { \
        acc[qm][qn][i][j] = __builtin_amdgcn_mfma_f32_16x16x32_bf16(af[i][0], bset[j][0], acc[qm][qn][i][j], 0, 0, 0); \
        acc[qm][qn][i][j] = __builtin_amdgcn_mfma_f32_16x16x32_bf16(af[i][1], bset[j][1], acc[qm][qn][i][j], 0, 0, 0); } \
    __builtin_amdgcn_s_setprio(0); } while (0)

  for (int kt = 0; kt < NT; ++kt) {
    const int bb = (kt & 1) << 16;
    const int ob = bb ^ 65536;
    const char* Lb = lds + bb;
#pragma unroll
    for (int j = 0; j < 2; ++j) {
      b1v[j][0] = *(const bf16x8*)(Lb + 49152 + boff0 + j * 2048);
      b1v[j][1] = *(const bf16x8*)(Lb + 49152 + boff1 + j * 2048);
    }
    if (kt + 1 < NT) G1_STAGE_B0(ob, kt + 1);
    SBAR(); SCHED0();
    G1_MFMA(0, 0, b0v);
    SCHED0(); SBAR();
    if (kt + 2 < NT) G1_STAGE_A0(bb, kt + 2);
    SBAR(); SCHED0();
    G1_MFMA(0, 1, b1v);
    SCHED0();
#pragma unroll
    for (int i = 0; i < 4; ++i) {
      af[i][0] = *(const bf16x8*)(Lb + 16384 + aoff0 + i * 2048);
      af[i][1] = *(const bf16x8*)(Lb + 16384 + aoff1 + i * 2048);
    }
    SBAR();
    if (kt + 2 < NT) G1_STAGE_B1(bb, kt + 2);
    SBAR(); SCHED0();
    G1_MFMA(1, 1, b1v);
    SCHED0(); SBAR();
    if (kt + 2 < NT) G1_STAGE_A1(bb, kt + 2);
    SBAR(); SCHED0();
    G1_MFMA(1, 0, b0v);
    SCHED0();
    if (kt + 2 < NT) { WAIT_VM6(); } else { WAIT_VM0(); }
    SBAR();
    if (kt + 1 < NT) {
      const char* Lo = lds + ob;
#pragma unroll
      for (int i = 0; i < 4; ++i) {
        af[i][0] = *(const bf16x8*)(Lo + aoff0 + i * 2048);
        af[i][1] = *(const bf16x8*)(Lo + aoff1 + i * 2048);
      }
#pragma unroll
      for (int j = 0; j < 2; ++j) {
        b0v[j][0] = *(const bf16x8*)(Lo + 32768 + boff0 + j * 2048);
        b0v[j][1] = *(const bf16x8*)(Lo + 32768 + boff1 + j * 2048);
      }
    }
  }

  // epilogue: j=0 gate, j=1 up for the same 16 inter cols
#pragma unroll
  for (int qm = 0; qm < 2; ++qm)
#pragma unroll
    for (int qn = 0; qn < 2; ++qn) {
      long col = (n0 + qn * 128 + wn * 32) / 2 + l16;
#pragma unroll
      for (int i = 0; i < 4; ++i)
#pragma unroll
        for (int r = 0; r < 4; ++r) {
          long m = m0 + qm * 128 + wm * 64 + i * 16 + lq * 4 + r;
          float g = acc[qm][qn][i][0][r], u = acc[qm][qn][i][1][r];
          float sv = g / (1.f + __expf(-g));
          inter[m * II + col] = f2bf(sv * u);
        }
    }
#undef G1_STAGE_A0
#undef G1_STAGE_A1
#undef G1_STAGE_B0
#undef G1_STAGE_B1
#undef G1_MFMA
}

// ---------- launcher ----------
extern "C" void kernel_launch(void* const* d_in, const int* in_sizes, int n_in,
                              void* d_out, int out_size, void* d_ws, size_t ws_size,
                              hipStream_t stream) {
  const float* x   = (const float*)d_in[0];
  const float* guw = (const float*)d_in[1];
  const float* dww = (const float*)d_in[2];
  const float* rg  = (const float*)d_in[3];
  const float* ru  = (const float*)d_in[4];
  const float* rd  = (const float*)d_in[5];
  const float* fg  = (const float*)d_in[6];
  const float* fu  = (const float*)d_in[7];
  const float* fd  = (const float*)d_in[8];
  const float* sc  = (const float*)d_in[9];
  const int*   tix = (const int*)d_in[10];
  float* out = (float*)d_out;
  char* ws = (char*)d_ws;

  size_t o = 0;
  u16* xb            = (u16*)(ws + o); o += (size_t)TT * HH * 2;
  u16* gup           = (u16*)(ws + o); o += (size_t)2 * II * HH * 2;
  u16* dwb           = (u16*)(ws + o); o += (size_t)HH * II * 2;
  char* inter_base   = ws + o;         o += (size_t)TT * II * 2;
  u16* inter         = (u16*)inter_base;
  u16* wdb           = (u16*)(ws + o); o += (size_t)8 * HH * 128 * 2;
  u16* irb           = (u16*)(ws + o); o += (size_t)TT * 128 * 2;
  int* cntp          = (int*)(ws + o); o += 256;
  int* offp          = (int*)(ws + o); o += 256;
  int* listp         = (int*)(ws + o); o += (size_t)TT * 4;
  size_t o_shared = o;
  u16* wabA          = (u16*)(ws + o_shared);
  float* psumA       = (float*)(ws + o_shared + 16777216);
  size_t needA = o_shared + 16777216 + (size_t)4 * TT * 256 * 4;
  u16* wabB          = (u16*)inter_base;
  float* psumB       = (float*)(inter_base + 16777216);
  bool pathA = ws_size >= needA;
  u16* wab  = pathA ? wabA  : wabB;
  float* psum = pathA ? psumA : psumB;

  hipFuncSetAttribute((const void*)gemm1_fused_kernel,
                      hipFuncAttributeMaxDynamicSharedMemorySize, 131072);
  hipFuncSetAttribute((const void*)gemm2_8p_kernel,
                      hipFuncAttributeMaxDynamicSharedMemorySize, 131072);
  hipFuncSetAttribute((const void*)adapter_psum_kernel,
                      hipFuncAttributeMaxDynamicSharedMemorySize, 82176);
  hipFuncSetAttribute((const void*)adapter_down2_kernel,
                      hipFuncAttributeMaxDynamicSharedMemorySize, 81920);

  cvt_xgup_kernel<<<2048, 256, 0, stream>>>(x, xb, guw, gup);
  prep_kernel<<<385, 256, 0, stream>>>(tix, cntp, offp, listp,
                                       rg, ru, fg, fu, wab, rd, fd, wdb);

  if (pathA) {
    gemm1_fused_kernel<<<G1_NGEMM + G1_NAUX, 512, 131072, stream>>>(
        xb, gup, inter, G1_NAUX, dww, dwb, wab, psum, cntp, offp, listp);
    adapter_reduce_kernel<<<2048, 256, 0, stream>>>(psum, sc, tix, irb);
  } else {
    adapter_psum_kernel<<<dim3(NSLOT, 64, 4), 512, 82176, stream>>>(
        xb, wab, cntp, offp, listp, psum);
    gemm1_fused_kernel<<<G1_NGEMM + 256, 512, 131072, stream>>>(
        xb, gup, inter, 256, dww, dwb, wab, psum, cntp, offp, listp);
    adapter_reduce_kernel<<<2048, 256, 0, stream>>>(psum, sc, tix, irb);
  }

  gemm2_8p_kernel<<<dim3(16, 16), 512, 131072, stream>>>(inter, dwb, out);
  adapter_down2_kernel<<<dim3(NSLOT, 64, 16), 512, 81920, stream>>>(
      irb, wdb, cntp, offp, listp, out);
}

// Round 15
// 1112.403 us; speedup vs baseline: 1.1580x; 1.0091x over previous
//
#include <hip/hip_runtime.h>
#include <hip/hip_bf16.h>

#define TT 4096L
#define HH 4096L
#define II 11008L
#define NSLOT 8

typedef short bf16x8 __attribute__((ext_vector_type(8)));
typedef float f32x4  __attribute__((ext_vector_type(4)));

#define WAIT_VM6() asm volatile("s_waitcnt vmcnt(6)" ::: "memory")
#define WAIT_VM0() asm volatile("s_waitcnt vmcnt(0)" ::: "memory")
#define SBAR() __builtin_amdgcn_s_barrier()
#define SCHED0() __builtin_amdgcn_sched_barrier(0)

#define G1_NGEMM 1376   // 16 m-tiles x 86 n-tiles, 4m x 8n XCD bricks
#define G1_NAUX  2304   // 256 dwb-cvt blocks + 2048 psum blocks

typedef unsigned short u16;

__device__ __forceinline__ u16 f2bf(float v) {
  union { float f; unsigned int u; } c; c.f = v;
  unsigned int u = c.u;
  u += 0x7fffu + ((u >> 16) & 1u);
  return (u16)(u >> 16);
}

__device__ __forceinline__ float bf2f(u16 v) {
  union { unsigned int u; float f; } c; c.u = ((unsigned int)v) << 16;
  return c.f;
}

__device__ __forceinline__ void load_lds16(const void* g, void* lds) {
  __builtin_amdgcn_global_load_lds(
      (const __attribute__((address_space(1))) unsigned int*)g,
      (__attribute__((address_space(3))) unsigned int*)lds, 16, 0, 0);
}

__device__ __forceinline__ ushort4 cvt4(float4 v) {
  ushort4 o;
  o.x = f2bf(v.x); o.y = f2bf(v.y); o.z = f2bf(v.z); o.w = f2bf(v.w);
  return o;
}

// ---------- fused convert: xb (plain) + gup (paired pack) ----------
__global__ __launch_bounds__(256) void cvt_xgup_kernel(
    const float* __restrict__ x, u16* __restrict__ xb,
    const float* __restrict__ guw, u16* __restrict__ gup) {
  const long NX = TT * HH / 4;
  const long NG = 2L * II * HH / 4;
  long i = (long)blockIdx.x * blockDim.x + threadIdx.x;
  long stride = (long)gridDim.x * blockDim.x;
  for (; i < NX + NG; i += stride) {
    if (i < NX) {
      ((ushort4*)xb)[i] = cvt4(((const float4*)x)[i]);
    } else {
      long g = i - NX;
      long grow = g >> 10;
      long q = g & 1023;
      long c16 = grow >> 5;
      int r = (int)(grow & 31);
      long src = (r < 16) ? (c16 * 16 + r) : (II + c16 * 16 + (r - 16));
      ((ushort4*)gup)[g] = cvt4(((const float4*)guw)[src * 1024 + q]);
    }
  }
}

// ---------- prep: bucket (block 0) + wab cvt (1..256) + wdb cvt (257..384) ----------
__global__ __launch_bounds__(256) void prep_kernel(
    const int* __restrict__ tix, int* __restrict__ cnt,
    int* __restrict__ off, int* __restrict__ list,
    const float* __restrict__ rg, const float* __restrict__ ru,
    const float* __restrict__ fg, const float* __restrict__ fu,
    u16* __restrict__ wab,
    const float* __restrict__ rd, const float* __restrict__ fd,
    u16* __restrict__ wdb) {
  int bid = blockIdx.x;
  int tid = threadIdx.x;
  if (bid == 0) {
    __shared__ int lc[NSLOT], lo[NSLOT], pc[NSLOT];
    if (tid < NSLOT) { lc[tid] = 0; pc[tid] = 0; }
    __syncthreads();
    for (int t = tid; t < TT; t += 256) atomicAdd(&lc[tix[t]], 1);
    __syncthreads();
    if (tid == 0) {
      int s = 0;
      for (int i = 0; i < NSLOT; ++i) { lo[i] = s; s += lc[i]; }
    }
    __syncthreads();
    for (int t = tid; t < TT; t += 256) {
      int s = tix[t];
      int p = atomicAdd(&pc[s], 1);
      list[lo[s] + p] = t;
    }
    if (tid < NSLOT) { cnt[tid] = lc[tid]; off[tid] = lo[tid]; }
  } else if (bid <= 256) {
    const long Q = 8L * 256 * HH / 4;
    long i = (long)(bid - 1) * 256 + tid;
    for (; i < Q; i += 256L * 256) {
      long grow = i >> 10, q = i & 1023;
      int s = (int)(grow >> 8), r = (int)(grow & 255);
      const float* src;
      int rr = r & 63;
      if (r < 64) src = rg; else if (r < 128) src = ru;
      else if (r < 192) src = fg; else src = fu;
      ((ushort4*)wab)[i] = cvt4(((const float4*)src)[((long)s * 64 + rr) * 1024 + q]);
    }
  } else {
    const long Q = 8L * HH * 128 / 4;
    long i = (long)(bid - 257) * 256 + tid;
    for (; i < Q; i += 128L * 256) {
      long rowg = i >> 5;
      int q = (int)(i & 31);
      float4 v = (q < 16) ? ((const float4*)rd)[rowg * 16 + q]
                          : ((const float4*)fd)[rowg * 16 + (q - 16)];
      ((ushort4*)wdb)[i] = cvt4(v);
    }
  }
}

// =====================================================================
// Adapter phase 1 body (MFMA, split-K=4) — shared by standalone + aux.
// =====================================================================
__device__ __forceinline__ void psum_body(
    char* lds, const u16* __restrict__ xb, const u16* __restrict__ wab,
    const int* __restrict__ cnt, const int* __restrict__ off,
    const int* __restrict__ list, float* __restrict__ psum,
    int s, int c, int kq, int tid) {
  int n = cnt[s];
  if (c * 64 >= n) return;
  int* tl = (int*)(lds + 81920);
  int base = off[s] + c * 64;
  int ntok = min(64, n - c * 64);
  if (tid < 64) tl[tid] = (tid < ntok) ? list[base + tid] : list[base];
  __syncthreads();
  const int w = tid >> 6, l = tid & 63, l16 = l & 15, lq = l >> 4;
  const int sslot = (tid & 7) ^ ((tid >> 3) & 7);
  const long kbase = (long)kq * 1024;
  const u16* xsrc = xb + (size_t)tl[tid >> 3] * HH + kbase + sslot * 8;
  const u16* wsrc = wab + ((size_t)s * 256 + (tid >> 3)) * HH + kbase + sslot * 8;
  const int wdst = w * 1024;

#define PS_STAGE(buf, t) do { \
    load_lds16(xsrc + (long)(t) * 64, lds + (buf) + wdst); \
    _Pragma("unroll") for (int r = 0; r < 4; ++r) \
      load_lds16(wsrc + (size_t)(r * 64) * HH + (long)(t) * 64, \
                 lds + (buf) + 8192 + r * 8192 + wdst); } while (0)

  const int sw = l16 & 7;
  f32x4 acc[4][2];
#pragma unroll
  for (int i = 0; i < 4; ++i)
#pragma unroll
    for (int j = 0; j < 2; ++j) acc[i][j] = (f32x4)0.f;

  PS_STAGE(0, 0);
  __syncthreads();
  for (int t = 0; t < 16; ++t) {
    const int cb = (t & 1) * 40960;
    if (t + 1 < 16) PS_STAGE(cb ^ 40960, t + 1);
    const char* Lb = lds + cb;
    bf16x8 av[4][2], bv[2][2];
#pragma unroll
    for (int i = 0; i < 4; ++i)
#pragma unroll
      for (int kh = 0; kh < 2; ++kh)
        av[i][kh] = *(const bf16x8*)(Lb + (i * 16 + l16) * 128 + (((kh * 4 + lq) ^ sw) * 16));
#pragma unroll
    for (int j = 0; j < 2; ++j)
#pragma unroll
      for (int kh = 0; kh < 2; ++kh)
        bv[j][kh] = *(const bf16x8*)(Lb + 8192 + (w * 32 + j * 16 + l16) * 128 + (((kh * 4 + lq) ^ sw) * 16));
#pragma unroll
    for (int i = 0; i < 4; ++i)
#pragma unroll
      for (int j = 0; j < 2; ++j) {
        acc[i][j] = __builtin_amdgcn_mfma_f32_16x16x32_bf16(av[i][0], bv[j][0], acc[i][j], 0, 0, 0);
        acc[i][j] = __builtin_amdgcn_mfma_f32_16x16x32_bf16(av[i][1], bv[j][1], acc[i][j], 0, 0, 0);
      }
    __syncthreads();
  }
  float* pb = psum + (size_t)kq * TT * 256;
#pragma unroll
  for (int i = 0; i < 4; ++i)
#pragma unroll
    for (int j = 0; j < 2; ++j)
#pragma unroll
      for (int r = 0; r < 4; ++r) {
        int tk = i * 16 + lq * 4 + r;
        pb[(size_t)tl[tk] * 256 + w * 32 + j * 16 + l16] = acc[i][j][r];
      }
#undef PS_STAGE
}

// standalone psum (path B)
__global__ __launch_bounds__(512) void adapter_psum_kernel(
    const u16* __restrict__ xb, const u16* __restrict__ wab,
    const int* __restrict__ cnt, const int* __restrict__ off,
    const int* __restrict__ list, float* __restrict__ psum) {
  extern __shared__ char lds[];
  psum_body(lds, xb, wab, cnt, off, list, psum,
            blockIdx.x, blockIdx.y, blockIdx.z, threadIdx.x);
}

// ---------- reduce split-K + SwiGLU + scale -> irb bf16 [T][128] ----------
__global__ __launch_bounds__(256) void adapter_reduce_kernel(
    const float* __restrict__ psum, const float* __restrict__ scales,
    const int* __restrict__ tix, u16* __restrict__ irb) {
  int idx = blockIdx.x * 256 + threadIdx.x;
  int t = idx >> 7, n = idx & 127;
  int a = n >> 6, nn = n & 63;
  int cg = a ? 128 + nn : nn;
  size_t b = (size_t)t * 256;
  float g = 0.f, u = 0.f;
#pragma unroll
  for (int kq = 0; kq < 4; ++kq) {
    g += psum[(size_t)kq * TT * 256 + b + cg];
    u += psum[(size_t)kq * TT * 256 + b + cg + 64];
  }
  float sc = scales[tix[t] * 2 + a];
  float sv = g / (1.f + __expf(-g));
  irb[idx] = f2bf(sv * u * sc);
}

// =====================================================================
// Adapter phase 2 (MFMA): adp[t][h] = irb[t][:] @ wdb[s][h][:]^T  (bf16,
// fresh writes; added into out by gemm2's epilogue)
// =====================================================================
__global__ __launch_bounds__(512) void adapter_down2_kernel(
    const u16* __restrict__ irb, const u16* __restrict__ wdb,
    const int* __restrict__ cnt, const int* __restrict__ off,
    const int* __restrict__ list, u16* __restrict__ adp) {
  extern __shared__ char lds[];
  __shared__ int tl[64];
  int s = blockIdx.x, c = blockIdx.y, hb = blockIdx.z;
  int n = cnt[s];
  if (c * 64 >= n) return;
  int base = off[s] + c * 64;
  int ntok = min(64, n - c * 64);
  int tid = threadIdx.x;
  if (tid < 64) tl[tid] = (tid < ntok) ? list[base + tid] : list[base];
  __syncthreads();
  const int w = tid >> 6, l = tid & 63, l16 = l & 15, lq = l >> 4;
  const int sslot = (tid & 15) ^ ((tid >> 4) & 15);
  const int wdst = w * 1024;
  const u16* isrc0 = irb + (size_t)tl[tid >> 4] * 128 + sslot * 8;
  const u16* isrc1 = irb + (size_t)tl[32 + (tid >> 4)] * 128 + sslot * 8;
  const u16* wsrc =
      wdb + ((size_t)s * HH + hb * 256 + (tid >> 4)) * 128 + sslot * 8;
  load_lds16(isrc0, lds + wdst);
  load_lds16(isrc1, lds + 8192 + wdst);
#pragma unroll
  for (int r = 0; r < 8; ++r)
    load_lds16(wsrc + (size_t)r * 4096, lds + 16384 + r * 8192 + wdst);
  __syncthreads();

  f32x4 acc[4][2];
#pragma unroll
  for (int i = 0; i < 4; ++i)
#pragma unroll
    for (int j = 0; j < 2; ++j) acc[i][j] = (f32x4)0.f;

#pragma unroll
  for (int kf = 0; kf < 4; ++kf) {
    bf16x8 av[4], bv[2];
#pragma unroll
    for (int i = 0; i < 4; ++i)
      av[i] = *(const bf16x8*)(lds + (i * 16 + l16) * 256 + (((kf * 4 + lq) ^ l16) * 16));
#pragma unroll
    for (int j = 0; j < 2; ++j)
      bv[j] = *(const bf16x8*)(lds + 16384 + (w * 32 + j * 16 + l16) * 256 + (((kf * 4 + lq) ^ l16) * 16));
#pragma unroll
    for (int i = 0; i < 4; ++i)
#pragma unroll
      for (int j = 0; j < 2; ++j)
        acc[i][j] = __builtin_amdgcn_mfma_f32_16x16x32_bf16(av[i], bv[j], acc[i][j], 0, 0, 0);
  }
#pragma unroll
  for (int i = 0; i < 4; ++i)
#pragma unroll
    for (int j = 0; j < 2; ++j)
#pragma unroll
      for (int r = 0; r < 4; ++r) {
        int tk = i * 16 + lq * 4 + r;
        if (tk < ntok) {
          size_t o = (size_t)tl[tk] * HH + hb * 256 + w * 32 + j * 16 + l16;
          adp[o] = f2bf(acc[i][j][r]);
        }
      }
}

// =====================================================================
// GEMM2: out = inter @ down_w^T + adp — 256x256, BK=64, 8-phase staggered
// frags, 4m x 8n XCD-brick mapping, 16x16x32 MFMA (round-10 best config).
// =====================================================================
__global__ __launch_bounds__(512, 2) void gemm2_8p_kernel(
    const u16* __restrict__ A,
    const u16* __restrict__ B,
    const u16* __restrict__ adp,
    float* __restrict__ C) {
  extern __shared__ char lds[];
  const long K = II;
  const int NT = (int)(K >> 6);
  const int tid = threadIdx.x;
  const int w = tid >> 6, l = tid & 63, l16 = l & 15, lq = l >> 4;
  const int wm = w >> 2, wn = w & 3;
  const int lin = blockIdx.y * 16 + blockIdx.x;      // nwg=256
  const int xc = lin & 7, rr_ = lin >> 3;            // rr_ in [0,32)
  const long m0 = (long)((xc >> 1) * 4 + (rr_ & 3)) * 256;
  const long n0 = (long)((xc & 1) * 8 + (rr_ >> 2)) * 256;
  const int wb = w * 1024;

  const int srow = tid >> 3;
  const int sslot = (tid & 7) ^ (srow & 7);
  const u16* sA00 = A + (m0 +       srow) * K + sslot * 8;
  const u16* sA01 = A + (m0 +  64 + srow) * K + sslot * 8;
  const u16* sA10 = A + (m0 + 128 + srow) * K + sslot * 8;
  const u16* sA11 = A + (m0 + 192 + srow) * K + sslot * 8;
  const u16* sB00 = B + (n0 +       srow) * K + sslot * 8;
  const u16* sB01 = B + (n0 +  64 + srow) * K + sslot * 8;
  const u16* sB10 = B + (n0 + 128 + srow) * K + sslot * 8;
  const u16* sB11 = B + (n0 + 192 + srow) * K + sslot * 8;

#define G2_STAGE_A0(bb, kt) do { \
    load_lds16(sA00 + (long)(kt) * 64, lds + (bb) + wb); \
    load_lds16(sA01 + (long)(kt) * 64, lds + (bb) + 8192 + wb); } while (0)
#define G2_STAGE_A1(bb, kt) do { \
    load_lds16(sA10 + (long)(kt) * 64, lds + (bb) + 16384 + wb); \
    load_lds16(sA11 + (long)(kt) * 64, lds + (bb) + 24576 + wb); } while (0)
#define G2_STAGE_B0(bb, kt) do { \
    load_lds16(sB00 + (long)(kt) * 64, lds + (bb) + 32768 + wb); \
    load_lds16(sB01 + (long)(kt) * 64, lds + (bb) + 40960 + wb); } while (0)
#define G2_STAGE_B1(bb, kt) do { \
    load_lds16(sB10 + (long)(kt) * 64, lds + (bb) + 49152 + wb); \
    load_lds16(sB11 + (long)(kt) * 64, lds + (bb) + 57344 + wb); } while (0)

  const int sw = l16 & 7;
  const int aoff0 = (wm * 64 + l16) * 128 + ((0 + lq) ^ sw) * 16;
  const int aoff1 = (wm * 64 + l16) * 128 + ((4 + lq) ^ sw) * 16;
  const int boff0 = (wn * 32 + l16) * 128 + ((0 + lq) ^ sw) * 16;
  const int boff1 = (wn * 32 + l16) * 128 + ((4 + lq) ^ sw) * 16;

  f32x4 acc[2][2][4][2];
#pragma unroll
  for (int qm = 0; qm < 2; ++qm)
#pragma unroll
    for (int qn = 0; qn < 2; ++qn)
#pragma unroll
      for (int i = 0; i < 4; ++i)
#pragma unroll
        for (int j = 0; j < 2; ++j) acc[qm][qn][i][j] = (f32x4)0.f;

  G2_STAGE_A0(0, 0); G2_STAGE_A1(0, 0); G2_STAGE_B0(0, 0); G2_STAGE_B1(0, 0);
  G2_STAGE_A0(65536, 1); G2_STAGE_B1(65536, 1); G2_STAGE_A1(65536, 1);
  WAIT_VM6();
  SBAR();

  bf16x8 af[4][2], b0v[2][2], b1v[2][2];
#pragma unroll
  for (int i = 0; i < 4; ++i) {
    af[i][0] = *(const bf16x8*)(lds + aoff0 + i * 2048);
    af[i][1] = *(const bf16x8*)(lds + aoff1 + i * 2048);
  }
#pragma unroll
  for (int j = 0; j < 2; ++j) {
    b0v[j][0] = *(const bf16x8*)(lds + 32768 + boff0 + j * 2048);
    b0v[j][1] = *(const bf16x8*)(lds + 32768 + boff1 + j * 2048);
  }

#define G2_MFMA(qm, qn, bset) do { \
    __builtin_amdgcn_s_setprio(1); \
    _Pragma("unroll") for (int i = 0; i < 4; ++i) \
      _Pragma("unroll") for (int j = 0; j < 2; ++j) { \
        acc[qm][qn][i][j] = __builtin_amdgcn_mfma_f32_16x16x32_bf16(af[i][0], bset[j][0], acc[qm][qn][i][j], 0, 0, 0); \
        acc[qm][qn][i][j] = __builtin_amdgcn_mfma_f32_16x16x32_bf16(af[i][1], bset[j][1], acc[qm][qn][i][j], 0, 0, 0); } \
    __builtin_amdgcn_s_setprio(0); } while (0)

  for (int kt = 0; kt < NT; ++kt) {
    const int bb = (kt & 1) << 16;
    const int ob = bb ^ 65536;
    const char* Lb = lds + bb;
#pragma unroll
    for (int j = 0; j < 2; ++j) {
      b1v[j][0] = *(const bf16x8*)(Lb + 49152 + boff0 + j * 2048);
      b1v[j][1] = *(const bf16x8*)(Lb + 49152 + boff1 + j * 2048);
    }
    if (kt + 1 < NT) G2_STAGE_B0(ob, kt + 1);
    SBAR(); SCHED0();
    G2_MFMA(0, 0, b0v);
    SCHED0(); SBAR();
    if (kt + 2 < NT) G2_STAGE_A0(bb, kt + 2);
    SBAR(); SCHED0();
    G2_MFMA(0, 1, b1v);
    SCHED0();
#pragma unroll
    for (int i = 0; i < 4; ++i) {
      af[i][0] = *(const bf16x8*)(Lb + 16384 + aoff0 + i * 2048);
      af[i][1] = *(const bf16x8*)(Lb + 16384 + aoff1 + i * 2048);
    }
    SBAR();
    if (kt + 2 < NT) G2_STAGE_B1(bb, kt + 2);
    SBAR(); SCHED0();
    G2_MFMA(1, 1, b1v);
    SCHED0(); SBAR();
    if (kt + 2 < NT) G2_STAGE_A1(bb, kt + 2);
    SBAR(); SCHED0();
    G2_MFMA(1, 0, b0v);
    SCHED0();
    if (kt + 2 < NT) { WAIT_VM6(); } else { WAIT_VM0(); }
    SBAR();
    if (kt + 1 < NT) {
      const char* Lo = lds + ob;
#pragma unroll
      for (int i = 0; i < 4; ++i) {
        af[i][0] = *(const bf16x8*)(Lo + aoff0 + i * 2048);
        af[i][1] = *(const bf16x8*)(Lo + aoff1 + i * 2048);
      }
#pragma unroll
      for (int j = 0; j < 2; ++j) {
        b0v[j][0] = *(const bf16x8*)(Lo + 32768 + boff0 + j * 2048);
        b0v[j][1] = *(const bf16x8*)(Lo + 32768 + boff1 + j * 2048);
      }
    }
  }

#pragma unroll
  for (int qm = 0; qm < 2; ++qm)
#pragma unroll
    for (int qn = 0; qn < 2; ++qn)
#pragma unroll
      for (int i = 0; i < 4; ++i)
#pragma unroll
        for (int j = 0; j < 2; ++j)
#pragma unroll
          for (int r = 0; r < 4; ++r) {
            long m = m0 + qm * 128 + wm * 64 + i * 16 + lq * 4 + r;
            long nn = n0 + qn * 128 + wn * 32 + j * 16 + l16;
            C[m * HH + nn] = acc[qm][qn][i][j][r] + bf2f(adp[m * HH + nn]);
          }
#undef G2_STAGE_A0
#undef G2_STAGE_A1
#undef G2_STAGE_B0
#undef G2_STAGE_B1
#undef G2_MFMA
}

// =====================================================================
// GEMM1 fused: swiglu(X @ gup^T), 8-phase staggered frags, 4m x 8n
// XCD-brick mapping; aux tail = dwb convert (aid<256) + psum (aid>=256).
// =====================================================================
__global__ __launch_bounds__(512, 2) void gemm1_fused_kernel(
    const u16* __restrict__ A,     // xb [TT][HH]
    const u16* __restrict__ B,     // gup [2I][HH] paired
    u16* __restrict__ inter,       // [TT][II]
    int naux,
    const float* __restrict__ dww, u16* __restrict__ dwb,
    const u16* __restrict__ wab, float* __restrict__ psum,
    const int* __restrict__ cnt, const int* __restrict__ off,
    const int* __restrict__ list) {
  extern __shared__ char lds[];
  const int lin = blockIdx.x;
  const int tid = threadIdx.x;

  if (lin >= G1_NGEMM) {
    int aid = lin - G1_NGEMM;
    if (aid >= naux) return;
    if (aid < 256) {
      const long Q = HH * II / 4;
      long i = (long)aid * 512 + tid;
      for (; i < Q; i += 256L * 512)
        ((ushort4*)dwb)[i] = cvt4(((const float4*)dww)[i]);
    } else {
      int p = aid - 256;                     // [0, 2048)
      psum_body(lds, A, wab, cnt, off, list, psum,
                p & 7, (p >> 3) & 63, p >> 9, tid);
    }
    return;
  }

  // ---------------- GEMM path (4m x 8n brick mapping) ----------------
  const int xc = lin & 7, s = lin >> 3;     // s in [0,172)
  const int wv = s >> 5, rr_ = s & 31;      // wv in [0,6); wv==5 has rr_<12
  const long m0 = (long)((xc >> 1) * 4 + (rr_ & 3)) * 256;
  const long n0 = (long)((xc & 1) * 43 + wv * 8 + (rr_ >> 2)) * 256;  // virtual

  const long K = HH;
  const int NT = (int)(K >> 6);             // 64
  const int w = tid >> 6, l = tid & 63, l16 = l & 15, lq = l >> 4;
  const int wm = w >> 2, wn = w & 3;
  const int wb = w * 1024;

  const int srow = tid >> 3;
  const int sslot = (tid & 7) ^ (srow & 7);
  const u16* sA00 = A + (m0 +       srow) * K + sslot * 8;
  const u16* sA01 = A + (m0 +  64 + srow) * K + sslot * 8;
  const u16* sA10 = A + (m0 + 128 + srow) * K + sslot * 8;
  const u16* sA11 = A + (m0 + 192 + srow) * K + sslot * 8;
  const u16* sB00 = B + (n0 +       srow) * K + sslot * 8;
  const u16* sB01 = B + (n0 +  64 + srow) * K + sslot * 8;
  const u16* sB10 = B + (n0 + 128 + srow) * K + sslot * 8;
  const u16* sB11 = B + (n0 + 192 + srow) * K + sslot * 8;

#define G1_STAGE_A0(bb, kt) do { \
    load_lds16(sA00 + (long)(kt) * 64, lds + (bb) + wb); \
    load_lds16(sA01 + (long)(kt) * 64, lds + (bb) + 8192 + wb); } while (0)
#define G1_STAGE_A1(bb, kt) do { \
    load_lds16(sA10 + (long)(kt) * 64, lds + (bb) + 16384 + wb); \
    load_lds16(sA11 + (long)(kt) * 64, lds + (bb) + 24576 + wb); } while (0)
#define G1_STAGE_B0(bb, kt) do { \
    load_lds16(sB00 + (long)(kt) * 64, lds + (bb) + 32768 + wb); \
    load_lds16(sB01 + (long)(kt) * 64, lds + (bb) + 40960 + wb); } while (0)
#define G1_STAGE_B1(bb, kt) do { \
    load_lds16(sB10 + (long)(kt) * 64, lds + (bb) + 49152 + wb); \
    load_lds16(sB11 + (long)(kt) * 64, lds + (bb) + 57344 + wb); } while (0)

  const int sw = l16 & 7;
  const int aoff0 = (wm * 64 + l16) * 128 + ((0 + lq) ^ sw) * 16;
  const int aoff1 = (wm * 64 + l16) * 128 + ((4 + lq) ^ sw) * 16;
  const int boff0 = (wn * 32 + l16) * 128 + ((0 + lq) ^ sw) * 16;
  const int boff1 = (wn * 32 + l16) * 128 + ((4 + lq) ^ sw) * 16;

  f32x4 acc[2][2][4][2];
#pragma unroll
  for (int qm = 0; qm < 2; ++qm)
#pragma unroll
    for (int qn = 0; qn < 2; ++qn)
#pragma unroll
      for (int i = 0; i < 4; ++i)
#pragma unroll
        for (int j = 0; j < 2; ++j) acc[qm][qn][i][j] = (f32x4)0.f;

  G1_STAGE_A0(0, 0); G1_STAGE_A1(0, 0); G1_STAGE_B0(0, 0); G1_STAGE_B1(0, 0);
  G1_STAGE_A0(65536, 1); G1_STAGE_B1(65536, 1); G1_STAGE_A1(65536, 1);
  WAIT_VM6();
  SBAR();

  bf16x8 af[4][2], b0v[2][2], b1v[2][2];
#pragma unroll
  for (int i = 0; i < 4; ++i) {
    af[i][0] = *(const bf16x8*)(lds + aoff0 + i * 2048);
    af[i][1] = *(const bf16x8*)(lds + aoff1 + i * 2048);
  }
#pragma unroll
  for (int j = 0; j < 2; ++j) {
    b0v[j][0] = *(const bf16x8*)(lds + 32768 + boff0 + j * 2048);
    b0v[j][1] = *(const bf16x8*)(lds + 32768 + boff1 + j * 2048);
  }

#define G1_MFMA(qm, qn, bset) do { \
    __builtin_amdgcn_s_setprio(1); \
    _Pragma("unroll") for (int i = 0; i < 4; ++i) \
      _Pragma("unroll") for (int j = 0; j < 2; ++j) { \
        acc[qm][qn][i][j] = __builtin_amdgcn_mfma_f32_16x16x32_bf16(af[i][0], bset[j][0], acc[qm][qn][i][j], 0, 0, 0); \
        acc[qm][qn][i][j] = __builtin_amdgcn_mfma_f32_16x16x32_bf16(af[i][1], bset[j][1], acc[qm][qn][i][j], 0, 0, 0); } \
    __builtin_amdgcn_s_setprio(0); } while (0)

  for (int kt = 0; kt < NT; ++kt) {
    const int bb = (kt & 1) << 16;
    const int ob = bb ^ 65536;
    const char* Lb = lds + bb;
#pragma unroll
    for (int j = 0; j < 2; ++j) {
      b1v[j][0] = *(const bf16x8*)(Lb + 49152 + boff0 + j * 2048);
      b1v[j][1] = *(const bf16x8*)(Lb + 49152 + boff1 + j * 2048);
    }
    if (kt + 1 < NT) G1_STAGE_B0(ob, kt + 1);
    SBAR(); SCHED0();
    G1_MFMA(0, 0, b0v);
    SCHED0(); SBAR();
    if (kt + 2 < NT) G1_STAGE_A0(bb, kt + 2);
    SBAR(); SCHED0();
    G1_MFMA(0, 1, b1v);
    SCHED0();
#pragma unroll
    for (int i = 0; i < 4; ++i) {
      af[i][0] = *(const bf16x8*)(Lb + 16384 + aoff0 + i * 2048);
      af[i][1] = *(const bf16x8*)(Lb + 16384 + aoff1 + i * 2048);
    }
    SBAR();
    if (kt + 2 < NT) G1_STAGE_B1(bb, kt + 2);
    SBAR(); SCHED0();
    G1_MFMA(1, 1, b1v);
    SCHED0(); SBAR();
    if (kt + 2 < NT) G1_STAGE_A1(bb, kt + 2);
    SBAR(); SCHED0();
    G1_MFMA(1, 0, b0v);
    SCHED0();
    if (kt + 2 < NT) { WAIT_VM6(); } else { WAIT_VM0(); }
    SBAR();
    if (kt + 1 < NT) {
      const char* Lo = lds + ob;
#pragma unroll
      for (int i = 0; i < 4; ++i) {
        af[i][0] = *(const bf16x8*)(Lo + aoff0 + i * 2048);
        af[i][1] = *(const bf16x8*)(Lo + aoff1 + i * 2048);
      }
#pragma unroll
      for (int j = 0; j < 2; ++j) {
        b0v[j][0] = *(const bf16x8*)(Lo + 32768 + boff0 + j * 2048);
        b0v[j][1] = *(const bf16x8*)(Lo + 32768 + boff1 + j * 2048);
      }
    }
  }

  // epilogue: j=0 gate, j=1 up for the same 16 inter cols
#pragma unroll
  for (int qm = 0; qm < 2; ++qm)
#pragma unroll
    for (int qn = 0; qn < 2; ++qn) {
      long col = (n0 + qn * 128 + wn * 32) / 2 + l16;
#pragma unroll
      for (int i = 0; i < 4; ++i)
#pragma unroll
        for (int r = 0; r < 4; ++r) {
          long m = m0 + qm * 128 + wm * 64 + i * 16 + lq * 4 + r;
          float g = acc[qm][qn][i][0][r], u = acc[qm][qn][i][1][r];
          float sv = g / (1.f + __expf(-g));
          inter[m * II + col] = f2bf(sv * u);
        }
    }
#undef G1_STAGE_A0
#undef G1_STAGE_A1
#undef G1_STAGE_B0
#undef G1_STAGE_B1
#undef G1_MFMA
}

// ---------- launcher ----------
extern "C" void kernel_launch(void* const* d_in, const int* in_sizes, int n_in,
                              void* d_out, int out_size, void* d_ws, size_t ws_size,
                              hipStream_t stream) {
  const float* x   = (const float*)d_in[0];
  const float* guw = (const float*)d_in[1];
  const float* dww = (const float*)d_in[2];
  const float* rg  = (const float*)d_in[3];
  const float* ru  = (const float*)d_in[4];
  const float* rd  = (const float*)d_in[5];
  const float* fg  = (const float*)d_in[6];
  const float* fu  = (const float*)d_in[7];
  const float* fd  = (const float*)d_in[8];
  const float* sc  = (const float*)d_in[9];
  const int*   tix = (const int*)d_in[10];
  float* out = (float*)d_out;
  char* ws = (char*)d_ws;

  size_t o = 0;
  u16* xb            = (u16*)(ws + o); o += (size_t)TT * HH * 2;
  u16* gup           = (u16*)(ws + o); o += (size_t)2 * II * HH * 2;
  u16* dwb           = (u16*)(ws + o); o += (size_t)HH * II * 2;
  char* inter_base   = ws + o;         o += (size_t)TT * II * 2;
  u16* inter         = (u16*)inter_base;
  u16* wdb           = (u16*)(ws + o); o += (size_t)8 * HH * 128 * 2;
  u16* irb           = (u16*)(ws + o); o += (size_t)TT * 128 * 2;
  int* cntp          = (int*)(ws + o); o += 256;
  int* offp          = (int*)(ws + o); o += 256;
  int* listp         = (int*)(ws + o); o += (size_t)TT * 4;
  size_t o_shared = o;
  u16* wabA          = (u16*)(ws + o_shared);
  float* psumA       = (float*)(ws + o_shared + 16777216);
  size_t needA = o_shared + 16777216 + (size_t)4 * TT * 256 * 4;
  u16* wabB          = (u16*)inter_base;
  float* psumB       = (float*)(inter_base + 16777216);
  bool pathA = ws_size >= needA;
  u16* wab  = pathA ? wabA  : wabB;
  float* psum = pathA ? psumA : psumB;
  // adp[T][H] bf16 aliases the gup region (gup dead after gemm1 completes;
  // adapter_down2 runs stream-after gemm1 in both paths).
  u16* adp = gup;

  hipFuncSetAttribute((const void*)gemm1_fused_kernel,
                      hipFuncAttributeMaxDynamicSharedMemorySize, 131072);
  hipFuncSetAttribute((const void*)gemm2_8p_kernel,
                      hipFuncAttributeMaxDynamicSharedMemorySize, 131072);
  hipFuncSetAttribute((const void*)adapter_psum_kernel,
                      hipFuncAttributeMaxDynamicSharedMemorySize, 82176);
  hipFuncSetAttribute((const void*)adapter_down2_kernel,
                      hipFuncAttributeMaxDynamicSharedMemorySize, 81920);

  cvt_xgup_kernel<<<2048, 256, 0, stream>>>(x, xb, guw, gup);
  prep_kernel<<<385, 256, 0, stream>>>(tix, cntp, offp, listp,
                                       rg, ru, fg, fu, wab, rd, fd, wdb);

  if (pathA) {
    gemm1_fused_kernel<<<G1_NGEMM + G1_NAUX, 512, 131072, stream>>>(
        xb, gup, inter, G1_NAUX, dww, dwb, wab, psum, cntp, offp, listp);
    adapter_reduce_kernel<<<2048, 256, 0, stream>>>(psum, sc, tix, irb);
  } else {
    // path B: psum (aliased into inter) must be consumed by reduce BEFORE
    // gemm1 overwrites inter.
    adapter_psum_kernel<<<dim3(NSLOT, 64, 4), 512, 82176, stream>>>(
        xb, wab, cntp, offp, listp, psum);
    adapter_reduce_kernel<<<2048, 256, 0, stream>>>(psum, sc, tix, irb);
    gemm1_fused_kernel<<<G1_NGEMM + 256, 512, 131072, stream>>>(
        xb, gup, inter, 256, dww, dwb, wab, psum, cntp, offp, listp);
  }

  // adapter contribution -> adp (fresh bf16 writes), then fused add in gemm2
  adapter_down2_kernel<<<dim3(NSLOT, 64, 16), 512, 81920, stream>>>(
      irb, wdb, cntp, offp, listp, adp);
  gemm2_8p_kernel<<<dim3(16, 16), 512, 131072, stream>>>(inter, dwb, adp, out);
}